// Round 5
// baseline (447.564 us; speedup 1.0000x reference)
//
#include <hip/hip_runtime.h>
#include <math.h>

#define HDIM 768
#define HIDD 512
#define NTOK 16384
#define NT 20
#define CHUNKS 128
#define CLEN 128

typedef unsigned short ushort_t;
typedef __attribute__((ext_vector_type(8))) short bf16x8;
typedef __attribute__((ext_vector_type(4))) float f32x4;

__device__ __forceinline__ float sigm(float x){ return 1.0f/(1.0f+expf(-x)); }

__device__ __forceinline__ ushort_t f2bf(float f){
    unsigned int u = __float_as_uint(f);
    unsigned int r = (u + 0x7fffu + ((u >> 16) & 1u)) >> 16;
    return (ushort_t)r;
}
__device__ __forceinline__ float bf2f(ushort_t b){
    return __uint_as_float(((unsigned int)b) << 16);
}

// ---------------------------------------------------------------------------
// Fused conversion kernel: blocks [0,1152) pack B (w_ih f/b gates i,g,o),
// blocks [1152, 13440) split x rows 1..16384 into bf16 hi/lo.
// ---------------------------------------------------------------------------
__global__ __launch_bounds__(256) void conv_kernel(
    const float* __restrict__ x,
    const float* __restrict__ wf, const float* __restrict__ wb,
    ushort_t* __restrict__ Ah, ushort_t* __restrict__ Al,
    ushort_t* __restrict__ Bh, ushort_t* __restrict__ Bl)
{
    const int bid = blockIdx.x;
    if (bid < 1152){
        int t = bid*256 + threadIdx.x;                 // 1536*192
        int n = t / 192, c4 = (t - n*192)*4;
        int dir = n / 768, nr = n - dir*768;
        int gate = nr >> 8, j = nr & 255;
        int wrow = j + ((gate==0)?0:((gate==1)?512:768));
        const float* src = dir ? wb : wf;
        const float4 v = *(const float4*)(src + (size_t)wrow*HDIM + c4);
        float f[4] = {v.x, v.y, v.z, v.w};
        ushort_t h[4], l[4];
        #pragma unroll
        for (int i=0;i<4;++i){
            h[i] = f2bf(f[i]);
            l[i] = f2bf(f[i] - bf2f(h[i]));
        }
        *(ushort4*)(Bh + (size_t)n*HDIM + c4) = make_ushort4(h[0],h[1],h[2],h[3]);
        *(ushort4*)(Bl + (size_t)n*HDIM + c4) = make_ushort4(l[0],l[1],l[2],l[3]);
    } else {
        int t = (bid-1152)*256 + threadIdx.x;          // 16384*192
        int row = t / 192, c4 = (t - row*192)*4;
        const float4 v = *(const float4*)(x + (size_t)(row+1)*HDIM + c4);
        float f[4] = {v.x, v.y, v.z, v.w};
        ushort_t h[4], l[4];
        #pragma unroll
        for (int i=0;i<4;++i){
            h[i] = f2bf(f[i]);
            l[i] = f2bf(f[i] - bf2f(h[i]));
        }
        *(ushort4*)(Ah + (size_t)row*HDIM + c4) = make_ushort4(h[0],h[1],h[2],h[3]);
        *(ushort4*)(Al + (size_t)row*HDIM + c4) = make_ushort4(l[0],l[1],l[2],l[3]);
    }
}

// ---------------------------------------------------------------------------
// Fused split-bf16 MFMA GEMM + gates + partial-feats epilogue.
// m-tile 64 x n-tile 128, BK=32, 3 gate passes, 4 blocks/CU.
// Register-staged pipeline: global loads for tile kt+1 issue BEFORE the
// compute of tile kt (latency hidden behind MFMA+ds_read); the barrier's
// implicit vmcnt(0) drain then lands after the loads are already done.
// LDS swizzle: global k8 g stored at slot (g+m)&3; reader (quad lq, row m)
// reads slot (lq+m)&3 -> 2-way (free) ds_read_b128, contiguous ds_write.
// MFMA order identical to prior rounds -> bit-identical results.
// ---------------------------------------------------------------------------
__global__ __launch_bounds__(256, 4) void gemm_fused(
    const ushort_t* __restrict__ Ah, const ushort_t* __restrict__ Al,
    const ushort_t* __restrict__ Bh, const ushort_t* __restrict__ Bl,
    const float* __restrict__ bihf, const float* __restrict__ bhhf,
    const float* __restrict__ bihb, const float* __restrict__ bhhb,
    const float* __restrict__ wtag, float* __restrict__ featsp)
{
    __shared__ __align__(16) char smem[32768];
    ushort_t* As_h = (ushort_t*)smem;              // 64x32 bf16 swizzled, 4KB
    ushort_t* As_l = (ushort_t*)(smem + 4096);     // 4KB
    ushort_t* Bs_h = (ushort_t*)(smem + 8192);     // 128x32, 8KB
    ushort_t* Bs_l = (ushort_t*)(smem + 16384);    // 8KB
    float* hbuf = (float*)smem;                    // epilogue: 32x129 f32 (16512B)
    float* wts  = (float*)(smem + 16512);          // epilogue: 20x128 f32 (10240B)

    const int tid = threadIdx.x;
    const int bx = blockIdx.x;
    const int xcd = bx & 7, bidx = bx >> 3;
    const int q = bidx & 3, mt = (bidx >> 2)*8 + xcd;   // 4 q-blocks share XCD
    const int dir = q >> 1, j0 = (q & 1)*128;
    const int row0 = mt*64;
    const float* __restrict__ bih = dir ? bihb : bihf;
    const float* __restrict__ bhh = dir ? bhhb : bhhf;

    const int lane = tid & 63, wv = tid >> 6;
    const int wm = wv >> 1, wn = wv & 1;
    const int lm = lane & 15, lq = lane >> 4;

    // ---- staging thread -> (row, stored-slot, global-k8) -------------------
    const int srA = tid >> 2;                     // A slot row (0..63)
    const int ssl = tid & 3;                      // stored slot
    const int gA  = (ssl - srA) & 3;              // global k8 for A
    const size_t aoffe = (size_t)(row0 + srA)*HDIM + gA*8;
    const int srB1 = 64 + srA;                    // B half-1 slot row
    const int gB1  = (ssl - srB1) & 3;
    const size_t boffe0 = (size_t)srB1*HDIM*0 + (size_t)srA*HDIM + gA*8; // half0 same as A pattern
    const size_t boffe1 = (size_t)srB1*HDIM + gB1*8;

    // ---- fragment ds_read offsets (ushort idx), swizzle-matched ------------
    int aoff_lds[2], boff_lds[4];
    #pragma unroll
    for (int f=0; f<2; ++f){
        int m = wm*32 + f*16 + lm;
        aoff_lds[f] = (m*4 + ((lq + m) & 3))*8;
    }
    #pragma unroll
    for (int f=0; f<4; ++f){
        int n = wn*64 + f*16 + lm;
        boff_lds[f] = (n*4 + ((lq + n) & 3))*8;
    }

    int jcol[4];
    #pragma unroll
    for (int fn=0; fn<4; ++fn) jcol[fn] = j0 + wn*64 + fn*16 + lm;

    float held[2][4][4];
    f32x4 acc[2][4];
    uint4 rAh, rAl, rBh0, rBh1, rBl0, rBl1;

    // initial prefetch (p=0, kt=0)
    {
        const size_t bb = (size_t)(dir*768 + j0)*HDIM;
        rAh  = *(const uint4*)(Ah + aoffe);
        rAl  = *(const uint4*)(Al + aoffe);
        rBh0 = *(const uint4*)(Bh + bb + boffe0);
        rBh1 = *(const uint4*)(Bh + bb + boffe1);
        rBl0 = *(const uint4*)(Bl + bb + boffe0);
        rBl1 = *(const uint4*)(Bl + bb + boffe1);
    }

    #pragma unroll 1
    for (int p=0; p<3; ++p){
        #pragma unroll
        for (int fm=0; fm<2; ++fm)
            #pragma unroll
            for (int fn=0; fn<4; ++fn)
                acc[fm][fn] = (f32x4){0.f,0.f,0.f,0.f};

        #pragma unroll 1
        for (int kt=0; kt<24; ++kt){
            __syncthreads();                       // prev readers done; loads drained
            *(uint4*)&As_h[(size_t)tid*8]        = rAh;
            *(uint4*)&As_l[(size_t)tid*8]        = rAl;
            *(uint4*)&Bs_h[(size_t)tid*8]        = rBh0;
            *(uint4*)&Bs_h[2048 + (size_t)tid*8] = rBh1;
            *(uint4*)&Bs_l[(size_t)tid*8]        = rBl0;
            *(uint4*)&Bs_l[2048 + (size_t)tid*8] = rBl1;
            __syncthreads();

            // issue next tile's loads (overlap with compute below)
            int nkt = kt + 1, np = p;
            if (nkt == 24){ nkt = 0; ++np; }
            if (np < 3){
                const int k0 = nkt*32;
                const size_t bb = (size_t)(dir*768 + np*256 + j0)*HDIM;
                rAh  = *(const uint4*)(Ah + aoffe + k0);
                rAl  = *(const uint4*)(Al + aoffe + k0);
                rBh0 = *(const uint4*)(Bh + bb + boffe0 + k0);
                rBh1 = *(const uint4*)(Bh + bb + boffe1 + k0);
                rBl0 = *(const uint4*)(Bl + bb + boffe0 + k0);
                rBl1 = *(const uint4*)(Bl + bb + boffe1 + k0);
            }

            bf16x8 afh[2], afl[2], bfh[4], bfl[4];
            #pragma unroll
            for (int f=0; f<2; ++f){
                afh[f] = *(const bf16x8*)&As_h[aoff_lds[f]];
                afl[f] = *(const bf16x8*)&As_l[aoff_lds[f]];
            }
            #pragma unroll
            for (int f=0; f<4; ++f){
                bfh[f] = *(const bf16x8*)&Bs_h[boff_lds[f]];
                bfl[f] = *(const bf16x8*)&Bs_l[boff_lds[f]];
            }
            #pragma unroll
            for (int fm=0; fm<2; ++fm)
                #pragma unroll
                for (int fn=0; fn<4; ++fn){
                    acc[fm][fn] = __builtin_amdgcn_mfma_f32_16x16x32_bf16(
                        afh[fm], bfh[fn], acc[fm][fn], 0, 0, 0);
                    acc[fm][fn] = __builtin_amdgcn_mfma_f32_16x16x32_bf16(
                        afl[fm], bfh[fn], acc[fm][fn], 0, 0, 0);
                    acc[fm][fn] = __builtin_amdgcn_mfma_f32_16x16x32_bf16(
                        afh[fm], bfl[fn], acc[fm][fn], 0, 0, 0);
                }
        }

        const int gbase = (p==0) ? 0 : ((p==1) ? 512 : 768);
        float bias[4];
        #pragma unroll
        for (int fn=0; fn<4; ++fn)
            bias[fn] = bih[gbase + jcol[fn]] + bhh[gbase + jcol[fn]];

        if (p==0){
            #pragma unroll
            for (int fm=0; fm<2; ++fm)
                #pragma unroll
                for (int fn=0; fn<4; ++fn)
                    #pragma unroll
                    for (int r=0; r<4; ++r)
                        held[fm][fn][r] = sigm(acc[fm][fn][r] + bias[fn]);
        } else if (p==1){
            #pragma unroll
            for (int fm=0; fm<2; ++fm)
                #pragma unroll
                for (int fn=0; fn<4; ++fn)
                    #pragma unroll
                    for (int r=0; r<4; ++r)
                        held[fm][fn][r] *= tanhf(acc[fm][fn][r] + bias[fn]);
        } else {
            float hv[2][4][4];
            #pragma unroll
            for (int fm=0; fm<2; ++fm)
                #pragma unroll
                for (int fn=0; fn<4; ++fn)
                    #pragma unroll
                    for (int r=0; r<4; ++r)
                        hv[fm][fn][r] = sigm(acc[fm][fn][r] + bias[fn]) * tanhf(held[fm][fn][r]);

            __syncthreads();   // all waves done with tiles before LDS reuse
            for (int i2=tid; i2<NT*128; i2+=256){
                int t = i2 >> 7, j = i2 & 127;
                wts[i2] = wtag[t*HIDD + dir*256 + j0 + j];
            }
            float* fq = featsp + (size_t)q * (NTOK*NT);
            #pragma unroll 1
            for (int ph=0; ph<2; ++ph){
                __syncthreads();
                if (wm == ph){
                    #pragma unroll
                    for (int fm=0; fm<2; ++fm)
                        #pragma unroll
                        for (int fn=0; fn<4; ++fn)
                            #pragma unroll
                            for (int r=0; r<4; ++r){
                                int mloc = fm*16 + lq*4 + r;         // 0..31
                                int jloc = wn*64 + fn*16 + lm;       // 0..127
                                hbuf[mloc*129 + jloc] = hv[fm][fn][r];
                            }
                }
                __syncthreads();
                const int mrow = tid & 31, grp = tid >> 5;           // 8 groups
                if (grp < 5){
                    const int tg0 = grp*4;
                    float s[4] = {0.f,0.f,0.f,0.f};
                    for (int j=0;j<128;++j){
                        float h = hbuf[mrow*129 + j];
                        #pragma unroll
                        for (int tt=0; tt<4; ++tt)
                            s[tt] = fmaf(h, wts[(tg0+tt)*128 + j], s[tt]);
                    }
                    const int mglob = row0 + ph*32 + mrow;
                    #pragma unroll
                    for (int tt=0; tt<4; ++tt)
                        fq[(size_t)mglob*NT + tg0 + tt] = s[tt];
                }
            }
        }
    }
}

// ---------------------------------------------------------------------------
// fl loader shared by chunkmat/replay: identical deterministic sum of the 4
// partial buffers + btag (bit-identical across both kernels).
// ---------------------------------------------------------------------------
__device__ __forceinline__ void load_fl(
    const float* __restrict__ featsp, const float* __restrict__ btg,
    float* fl, int c, int tid, int nthr)
{
    const float4* p0 = (const float4*)(featsp);
    const float4* p1 = (const float4*)(featsp + (size_t)NTOK*NT);
    const float4* p2 = (const float4*)(featsp + (size_t)2*NTOK*NT);
    const float4* p3 = (const float4*)(featsp + (size_t)3*NTOK*NT);
    const int base = c*(CLEN*NT/4);
    for (int idx=tid; idx<CLEN*NT/4; idx+=nthr){
        float4 a = p0[base+idx], b = p1[base+idx];
        float4 d = p2[base+idx], e = p3[base+idx];
        float4 v;
        v.x = (a.x+b.x)+(d.x+e.x);
        v.y = (a.y+b.y)+(d.y+e.y);
        v.z = (a.z+b.z)+(d.z+e.z);
        v.w = (a.w+b.w)+(d.w+e.w);
        int t0 = (idx*4) % 20;
        v.x += btg[t0]; v.y += btg[t0+1]; v.z += btg[t0+2]; v.w += btg[t0+3];
        ((float4*)fl)[idx] = v;
    }
}

// ---------------------------------------------------------------------------
// V1: per-chunk max-plus matrix product P_c (20x20). One block per chunk.
// ---------------------------------------------------------------------------
__global__ __launch_bounds__(512) void vit_chunkmat(
    const float* __restrict__ featsp, const float* __restrict__ btag,
    const float* __restrict__ trans, float* __restrict__ Pall)
{
    __shared__ float fl[CLEN*NT];
    __shared__ float Pb[2][NT*NT];
    const int c = blockIdx.x, tid = threadIdx.x;
    load_fl(featsp, btag, fl, c, tid, 512);
    const bool act = tid < NT*NT;
    const int i = tid/20, j = tid - i*20;
    float tr[NT];
    if (act){
        #pragma unroll
        for (int k=0;k<NT;++k) tr[k] = trans[i*NT+k];
        Pb[0][tid] = (i==j) ? 0.f : -1e30f;
    }
    __syncthreads();
    int cur = 0;
    for (int t=0;t<CLEN;++t){
        float m = -3.0e38f;
        if (act){
            #pragma unroll
            for (int k=0;k<NT;++k) m = fmaxf(m, tr[k] + Pb[cur][k*NT+j]);
            m += fl[t*NT+i];
            Pb[cur^1][tid] = m;
        }
        __syncthreads();
        cur ^= 1;
    }
    if (act) Pall[(size_t)c*(NT*NT) + tid] = Pb[cur][tid];
}

// ---------------------------------------------------------------------------
// V2: sequential chunk scan -> fv at chunk starts + terminal argmax/score.
// ---------------------------------------------------------------------------
__global__ __launch_bounds__(128) void vit_scan(
    const float* __restrict__ Pall, const float* __restrict__ trans,
    float* __restrict__ fvstart, float* __restrict__ dout, int* __restrict__ bestws)
{
    __shared__ float Pb[NT*NT];
    __shared__ float fv[NT];
    const int tid = threadIdx.x;
    float4 pn = {0.f,0.f,0.f,0.f};
    if (tid<100) pn = ((const float4*)Pall)[tid];
    if (tid<NT) fv[tid] = (tid==18) ? 0.f : -10000.f;
    for (int c=0;c<CHUNKS;++c){
        if (tid<100) ((float4*)Pb)[tid] = pn;
        if (tid<100 && c+1<CHUNKS) pn = ((const float4*)(Pall + (size_t)(c+1)*(NT*NT)))[tid];
        __syncthreads();
        if (tid<NT) fvstart[c*NT+tid] = fv[tid];
        float nf = -3.0e38f;
        if (tid<NT){
            #pragma unroll
            for (int j=0;j<NT;++j) nf = fmaxf(nf, Pb[tid*NT+j] + fv[j]);
        }
        __syncthreads();
        if (tid<NT) fv[tid] = nf;
    }
    __syncthreads();
    if (tid==0){
        float best = -3.0e38f; int bidx = 0;
        for (int j=0;j<NT;++j){
            float tv = fv[j] + trans[19*NT+j];
            if (tv > best){ best = tv; bidx = j; }
        }
        dout[0] = best;
        bestws[0] = bidx;
    }
}

// ---------------------------------------------------------------------------
// V3: exact per-step replay (reference argmax semantics) -> backpointers + H_c
// ---------------------------------------------------------------------------
__global__ __launch_bounds__(64) void vit_replay(
    const float* __restrict__ featsp, const float* __restrict__ btag,
    const float* __restrict__ trans, const float* __restrict__ fvstart,
    unsigned int* __restrict__ bpout, int* __restrict__ Hout)
{
    __shared__ float fl[CLEN*NT];
    __shared__ float fv[NT];
    __shared__ unsigned char bp[CLEN*NT];
    const int c = blockIdx.x, tid = threadIdx.x;
    load_fl(featsp, btag, fl, c, tid, 64);
    float tr[NT];
    if (tid<NT){
        fv[tid] = fvstart[c*NT+tid];
        #pragma unroll
        for (int k=0;k<NT;++k) tr[k] = trans[tid*NT+k];
    }
    __syncthreads();
    for (int t=0;t<CLEN;++t){
        float best = 0.f; int bj = 0;
        if (tid<NT){
            best = tr[0] + fv[0];
            #pragma unroll
            for (int j=1;j<NT;++j){
                float v = tr[j] + fv[j];
                if (v > best){ best = v; bj = j; }
            }
        }
        __syncthreads();
        if (tid<NT){
            fv[tid] = best + fl[t*NT+tid];
            bp[t*NT+tid] = (unsigned char)bj;
        }
        __syncthreads();
    }
    for (int idx=tid; idx<CLEN*NT/4; idx+=64)
        bpout[(size_t)c*(CLEN*NT/4) + idx] = ((unsigned int*)bp)[idx];
    if (tid<NT){
        int m = tid;
        for (int t=CLEN-1;t>=0;--t) m = bp[t*NT+m];
        Hout[c*NT+tid] = m;
    }
}

// ---------------------------------------------------------------------------
// V4 (fused): each block walks the composed chunk maps from bestws down to
// its own chunk, then backtracks its chunk and writes the path slice.
// ---------------------------------------------------------------------------
__global__ __launch_bounds__(64) void bt_fill(
    const unsigned int* __restrict__ bpin, const int* __restrict__ Hin,
    const int* __restrict__ bestws, float* __restrict__ dout)
{
    __shared__ int Hl[CHUNKS*NT];
    __shared__ unsigned char bp[CLEN*NT];
    __shared__ float ob[CLEN];
    const int c = blockIdx.x, tid = threadIdx.x;
    for (int idx=tid; idx<CHUNKS*NT; idx+=64) Hl[idx] = Hin[idx];
    for (int idx=tid; idx<CLEN*NT/4; idx+=64)
        ((unsigned int*)bp)[idx] = bpin[(size_t)c*(CLEN*NT/4) + idx];
    __syncthreads();
    if (tid==0){
        int e = bestws[0];
        for (int cc=CHUNKS-1; cc>c; --cc) e = Hl[cc*NT+e];
        for (int t=CLEN-1;t>=0;--t){ ob[t] = (float)e; e = bp[t*NT+e]; }
    }
    __syncthreads();
    for (int idx=tid; idx<CLEN; idx+=64)
        dout[1 + c*CLEN + idx] = ob[idx];
}

// ---------------------------------------------------------------------------
extern "C" void kernel_launch(void* const* d_in, const int* in_sizes, int n_in,
                              void* d_out, int out_size, void* d_ws, size_t ws_size,
                              hipStream_t stream)
{
    const float* x    = (const float*)d_in[0];
    const float* wf   = (const float*)d_in[1];
    const float* bihf = (const float*)d_in[3];
    const float* bhhf = (const float*)d_in[4];
    const float* wb   = (const float*)d_in[5];
    const float* bihb = (const float*)d_in[7];
    const float* bhhb = (const float*)d_in[8];
    const float* wtag = (const float*)d_in[9];
    const float* btag = (const float*)d_in[10];
    const float* trans= (const float*)d_in[11];
    float* out = (float*)d_out;

    char* w = (char*)d_ws;
    ushort_t* Ah = (ushort_t*)w;         w += 25165824;   // 16384*768*2
    ushort_t* Al = (ushort_t*)w;         w += 25165824;
    ushort_t* Bh = (ushort_t*)w;         w += 2359296;    // 1536*768*2
    ushort_t* Bl = (ushort_t*)w;         w += 2359296;
    float* featsp = (float*)w;           w += 5242880;    // 4 * 16384*20 * 4B
    float* Pall  = (float*)w;            w += 204800;     // 128*400*4
    float* fvst  = (float*)w;            w += 10240;      // 128*20*4
    int* Hmap    = (int*)w;              w += 10240;      // 128*20*4
    unsigned int* bp = (unsigned int*)w; w += 327680;     // 16384*20 bytes
    int* best    = (int*)w;

    conv_kernel<<<13440, 256, 0, stream>>>(x, wf, wb, Ah, Al, Bh, Bl);
    gemm_fused<<<1024, 256, 0, stream>>>(Ah, Al, Bh, Bl, bihf, bhhf, bihb, bhhb,
                                         wtag, featsp);
    vit_chunkmat<<<CHUNKS, 512, 0, stream>>>(featsp, btag, trans, Pall);
    vit_scan<<<1, 128, 0, stream>>>(Pall, trans, fvst, out, best);
    vit_replay<<<CHUNKS, 64, 0, stream>>>(featsp, btag, trans, fvst, bp, Hmap);
    bt_fill<<<CHUNKS, 64, 0, stream>>>(bp, Hmap, best, out);
}

// Round 6
// 432.555 us; speedup vs baseline: 1.0347x; 1.0347x over previous
//
#include <hip/hip_runtime.h>
#include <math.h>

#define HDIM 768
#define HIDD 512
#define NTOK 16384
#define NT 20
#define CHUNKS 128
#define CLEN 128

typedef unsigned short ushort_t;
typedef __attribute__((ext_vector_type(8))) short bf16x8;
typedef __attribute__((ext_vector_type(4))) float f32x4;

__device__ __forceinline__ float sigm(float x){ return 1.0f/(1.0f+expf(-x)); }

__device__ __forceinline__ ushort_t f2bf(float f){
    unsigned int u = __float_as_uint(f);
    unsigned int r = (u + 0x7fffu + ((u >> 16) & 1u)) >> 16;
    return (ushort_t)r;
}
__device__ __forceinline__ float bf2f(ushort_t b){
    return __uint_as_float(((unsigned int)b) << 16);
}

#define GLD16(gp, lp) __builtin_amdgcn_global_load_lds( \
    (const __attribute__((address_space(1))) void*)(gp), \
    (__attribute__((address_space(3))) void*)(lp), 16, 0, 0)

union U8 { ushort_t u[8]; uint4 v; };

// ---------------------------------------------------------------------------
// conv: pack w_ih_{f,b} gates {i,g,o} -> Bh/Bl bf16 (1536x768). B only —
// x is now converted in-register inside the GEMM.
// ---------------------------------------------------------------------------
__global__ __launch_bounds__(256) void conv_kernel(
    const float* __restrict__ wf, const float* __restrict__ wb,
    ushort_t* __restrict__ Bh, ushort_t* __restrict__ Bl)
{
    int t = blockIdx.x*256 + threadIdx.x;          // 1536*192
    int n = t / 192, c4 = (t - n*192)*4;
    int dir = n / 768, nr = n - dir*768;
    int gate = nr >> 8, j = nr & 255;
    int wrow = j + ((gate==0)?0:((gate==1)?512:768));
    const float* src = dir ? wb : wf;
    const float4 v = *(const float4*)(src + (size_t)wrow*HDIM + c4);
    float f[4] = {v.x, v.y, v.z, v.w};
    ushort_t h[4], l[4];
    #pragma unroll
    for (int i=0;i<4;++i){
        h[i] = f2bf(f[i]);
        l[i] = f2bf(f[i] - bf2f(h[i]));
    }
    *(ushort4*)(Bh + (size_t)n*HDIM + c4) = make_ushort4(h[0],h[1],h[2],h[3]);
    *(ushort4*)(Bl + (size_t)n*HDIM + c4) = make_ushort4(l[0],l[1],l[2],l[3]);
}

// ---------------------------------------------------------------------------
// Fused split-bf16 MFMA GEMM + gates + partial-feats epilogue.
// m-tile 64 x n-tile 128, BK=32, 3 gate passes, 40 KB LDS -> 4 blocks/CU.
// A: fp32 x loaded to regs during the previous tile's compute, converted to
//    bf16 hi/lo in-register (VALU pipe overlaps MFMA), ds_written at tile top.
// B: pre-split Bh/Bl streamed via global_load_lds into a double-buffered LDS
//    region; the issue point is a full compute-phase before the draining
//    barrier -> latency hidden.
// LDS chunk placement (16B chunks): C(m,k8) = (m>>1)*8 + (((m&1)*4+k8)^((m>>1)&7))
// -> every 16-lane read phase hits all 8 bank groups exactly 2x (free), and
// staging writes are contiguous. MFMA order unchanged -> bit-identical accs.
// ---------------------------------------------------------------------------
__global__ __launch_bounds__(256, 2) void gemm_fused(
    const float* __restrict__ x,
    const ushort_t* __restrict__ Bh, const ushort_t* __restrict__ Bl,
    const float* __restrict__ bihf, const float* __restrict__ bhhf,
    const float* __restrict__ bihb, const float* __restrict__ bhhb,
    const float* __restrict__ wtag, float* __restrict__ featsp)
{
    __shared__ __align__(16) char smem[40960];
    ushort_t* As_h = (ushort_t*)smem;                    // 4 KB
    ushort_t* As_l = (ushort_t*)(smem + 4096);           // 4 KB
    // B dbuf: buf0 h@8192 l@16384, buf1 h@24576 l@32768  (8 KB each)
    float* hbuf = (float*)smem;                          // epilogue 32x129 f32
    float* wts  = (float*)(smem + 16512);                // epilogue 20x128 f32

    const int tid = threadIdx.x;
    const int bx = blockIdx.x;
    const int xcd = bx & 7, bidx = bx >> 3;
    const int q = bidx & 3, mt = (bidx >> 2)*8 + xcd;    // 4 q-blocks share XCD
    const int dir = q >> 1, j0 = (q & 1)*128;
    const int row0 = mt*64;
    const float* __restrict__ bih = dir ? bihb : bihf;
    const float* __restrict__ bhh = dir ? bhhb : bhhf;

    const int lane = tid & 63, wv = tid >> 6;
    const int wm = wv >> 1, wn = wv & 1;
    const int lm = lane & 15, lq = lane >> 4;
    const int wb8 = (tid & 192) * 8;                     // wave-uniform ushort base

    // ---- staging decode: chunk C=tid -> (row, k8) under pair swizzle ------
    const int P_ = tid >> 3, s_ = tid & 7;
    const int q_ = s_ ^ (P_ & 7);
    const int mA = (P_ << 1) | (q_ >> 2);                // A row 0..63 (P_ 0..31)
    const int k8s = q_ & 3;                              // shared by A and B
    const int nB  = mA;                                  // B rows 0..63 (first half)
    const float* aSrc = x + (size_t)(row0 + mA + 1)*HDIM + k8s*8;
    const int bOff = nB*HDIM + k8s*8;                    // B second half: +64*HDIM

    // ---- fragment ds_read offsets (ushort idx) ----------------------------
    int aoff[2], boff[4];
    #pragma unroll
    for (int f=0; f<2; ++f){
        int m = wm*32 + f*16 + lm;
        aoff[f] = ((m>>1)*8 + ((((m&1)<<2)|lq) ^ ((m>>1)&7)))*8;
    }
    #pragma unroll
    for (int f=0; f<4; ++f){
        int n = wn*64 + f*16 + lm;
        boff[f] = ((n>>1)*8 + ((((n&1)<<2)|lq) ^ ((n>>1)&7)))*8;
    }

    int jcol[4];
    #pragma unroll
    for (int fn=0; fn<4; ++fn) jcol[fn] = j0 + wn*64 + fn*16 + lm;

    float held[2][4][4];
    f32x4 acc[2][4];
    uint4 rh, rl;                                        // converted A staging

    // ---- initial prefetch (p=0, kt=0) -------------------------------------
    {
        const size_t bb = (size_t)(dir*768 + j0)*HDIM;
        GLD16(Bh + bb + bOff,            smem + 8192  + wb8*2);
        GLD16(Bh + bb + bOff + 64*HDIM,  smem + 12288 + wb8*2);
        GLD16(Bl + bb + bOff,            smem + 16384 + wb8*2);
        GLD16(Bl + bb + bOff + 64*HDIM,  smem + 20480 + wb8*2);
        float4 ra0 = *(const float4*)(aSrc);
        float4 ra1 = *(const float4*)(aSrc + 4);
        float f[8] = {ra0.x,ra0.y,ra0.z,ra0.w,ra1.x,ra1.y,ra1.z,ra1.w};
        U8 h8, l8;
        #pragma unroll
        for (int i=0;i<8;++i){
            ushort_t h = f2bf(f[i]);
            h8.u[i] = h; l8.u[i] = f2bf(f[i] - bf2f(h));
        }
        rh = h8.v; rl = l8.v;
    }

    #pragma unroll 1
    for (int p=0; p<3; ++p){
        #pragma unroll
        for (int fm=0; fm<2; ++fm)
            #pragma unroll
            for (int fn=0; fn<4; ++fn)
                acc[fm][fn] = (f32x4){0.f,0.f,0.f,0.f};

        #pragma unroll 1
        for (int kt=0; kt<24; ++kt){
            __syncthreads();               // readers done; B(kt) GLD16 drained
            *(uint4*)&As_h[tid*8] = rh;
            *(uint4*)&As_l[tid*8] = rl;
            __syncthreads();

            // prefetch (kt+1): B -> alt LDS buffer, A -> regs + convert
            int nkt = kt + 1, np = p;
            if (nkt == 24){ nkt = 0; ++np; }
            if (np < 3){
                const int k0n = nkt*32;
                const size_t bb = (size_t)(dir*768 + np*256 + j0)*HDIM + k0n;
                char* bh_d = smem + 8192 + (nkt&1)*16384;
                GLD16(Bh + bb + bOff,           bh_d + wb8*2);
                GLD16(Bh + bb + bOff + 64*HDIM, bh_d + 4096 + wb8*2);
                GLD16(Bl + bb + bOff,           bh_d + 8192 + wb8*2);
                GLD16(Bl + bb + bOff + 64*HDIM, bh_d + 12288 + wb8*2);
                float4 ra0 = *(const float4*)(aSrc + k0n);
                float4 ra1 = *(const float4*)(aSrc + k0n + 4);
                float f[8] = {ra0.x,ra0.y,ra0.z,ra0.w,ra1.x,ra1.y,ra1.z,ra1.w};
                U8 h8, l8;
                #pragma unroll
                for (int i=0;i<8;++i){
                    ushort_t h = f2bf(f[i]);
                    h8.u[i] = h; l8.u[i] = f2bf(f[i] - bf2f(h));
                }
                rh = h8.v; rl = l8.v;
            }

            // compute tile kt
            const ushort_t* Bsh = (const ushort_t*)(smem + 8192 + (kt&1)*16384);
            const ushort_t* Bsl = (const ushort_t*)(smem + 16384 + (kt&1)*16384);
            bf16x8 afh[2], afl[2];
            #pragma unroll
            for (int f=0; f<2; ++f){
                afh[f] = *(const bf16x8*)&As_h[aoff[f]];
                afl[f] = *(const bf16x8*)&As_l[aoff[f]];
            }
            #pragma unroll
            for (int fn=0; fn<4; ++fn){
                bf16x8 bh = *(const bf16x8*)&Bsh[boff[fn]];
                bf16x8 bl = *(const bf16x8*)&Bsl[boff[fn]];
                #pragma unroll
                for (int fm=0; fm<2; ++fm){
                    acc[fm][fn] = __builtin_amdgcn_mfma_f32_16x16x32_bf16(
                        afh[fm], bh, acc[fm][fn], 0, 0, 0);
                    acc[fm][fn] = __builtin_amdgcn_mfma_f32_16x16x32_bf16(
                        afl[fm], bh, acc[fm][fn], 0, 0, 0);
                    acc[fm][fn] = __builtin_amdgcn_mfma_f32_16x16x32_bf16(
                        afh[fm], bl, acc[fm][fn], 0, 0, 0);
                }
            }
        }

        const int gbase = (p==0) ? 0 : ((p==1) ? 512 : 768);
        float bias[4];
        #pragma unroll
        for (int fn=0; fn<4; ++fn)
            bias[fn] = bih[gbase + jcol[fn]] + bhh[gbase + jcol[fn]];

        if (p==0){
            #pragma unroll
            for (int fm=0; fm<2; ++fm)
                #pragma unroll
                for (int fn=0; fn<4; ++fn)
                    #pragma unroll
                    for (int r=0; r<4; ++r)
                        held[fm][fn][r] = sigm(acc[fm][fn][r] + bias[fn]);
        } else if (p==1){
            #pragma unroll
            for (int fm=0; fm<2; ++fm)
                #pragma unroll
                for (int fn=0; fn<4; ++fn)
                    #pragma unroll
                    for (int r=0; r<4; ++r)
                        held[fm][fn][r] *= tanhf(acc[fm][fn][r] + bias[fn]);
        } else {
            float hv[2][4][4];
            #pragma unroll
            for (int fm=0; fm<2; ++fm)
                #pragma unroll
                for (int fn=0; fn<4; ++fn)
                    #pragma unroll
                    for (int r=0; r<4; ++r)
                        hv[fm][fn][r] = sigm(acc[fm][fn][r] + bias[fn]) * tanhf(held[fm][fn][r]);

            __syncthreads();   // all tile reads done before LDS reuse
            for (int i2=tid; i2<NT*128; i2+=256){
                int t = i2 >> 7, j = i2 & 127;
                wts[i2] = wtag[t*HIDD + dir*256 + j0 + j];
            }
            float* fq = featsp + (size_t)q * (NTOK*NT);
            #pragma unroll 1
            for (int ph=0; ph<2; ++ph){
                __syncthreads();
                if (wm == ph){
                    #pragma unroll
                    for (int fm=0; fm<2; ++fm)
                        #pragma unroll
                        for (int fn=0; fn<4; ++fn)
                            #pragma unroll
                            for (int r=0; r<4; ++r){
                                int mloc = fm*16 + lq*4 + r;         // 0..31
                                int jloc = wn*64 + fn*16 + lm;       // 0..127
                                hbuf[mloc*129 + jloc] = hv[fm][fn][r];
                            }
                }
                __syncthreads();
                const int mrow = tid & 31, grp = tid >> 5;           // 8 groups
                if (grp < 5){
                    const int tg0 = grp*4;
                    float s[4] = {0.f,0.f,0.f,0.f};
                    for (int j=0;j<128;++j){
                        float h = hbuf[mrow*129 + j];
                        #pragma unroll
                        for (int tt=0; tt<4; ++tt)
                            s[tt] = fmaf(h, wts[(tg0+tt)*128 + j], s[tt]);
                    }
                    const int mglob = row0 + ph*32 + mrow;
                    #pragma unroll
                    for (int tt=0; tt<4; ++tt)
                        fq[(size_t)mglob*NT + tg0 + tt] = s[tt];
                }
            }
        }
    }
}

// ---------------------------------------------------------------------------
// fl loader shared by chunkmat/replay: identical deterministic sum of the 4
// partial buffers + btag (bit-identical across both kernels).
// ---------------------------------------------------------------------------
__device__ __forceinline__ void load_fl(
    const float* __restrict__ featsp, const float* __restrict__ btg,
    float* fl, int c, int tid, int nthr)
{
    const float4* p0 = (const float4*)(featsp);
    const float4* p1 = (const float4*)(featsp + (size_t)NTOK*NT);
    const float4* p2 = (const float4*)(featsp + (size_t)2*NTOK*NT);
    const float4* p3 = (const float4*)(featsp + (size_t)3*NTOK*NT);
    const int base = c*(CLEN*NT/4);
    for (int idx=tid; idx<CLEN*NT/4; idx+=nthr){
        float4 a = p0[base+idx], b = p1[base+idx];
        float4 d = p2[base+idx], e = p3[base+idx];
        float4 v;
        v.x = (a.x+b.x)+(d.x+e.x);
        v.y = (a.y+b.y)+(d.y+e.y);
        v.z = (a.z+b.z)+(d.z+e.z);
        v.w = (a.w+b.w)+(d.w+e.w);
        int t0 = (idx*4) % 20;
        v.x += btg[t0]; v.y += btg[t0+1]; v.z += btg[t0+2]; v.w += btg[t0+3];
        ((float4*)fl)[idx] = v;
    }
}

// ---------------------------------------------------------------------------
// V1: per-chunk max-plus matrix product P_c (20x20). One block per chunk.
// ---------------------------------------------------------------------------
__global__ __launch_bounds__(512) void vit_chunkmat(
    const float* __restrict__ featsp, const float* __restrict__ btag,
    const float* __restrict__ trans, float* __restrict__ Pall)
{
    __shared__ float fl[CLEN*NT];
    __shared__ float Pb[2][NT*NT];
    const int c = blockIdx.x, tid = threadIdx.x;
    load_fl(featsp, btag, fl, c, tid, 512);
    const bool act = tid < NT*NT;
    const int i = tid/20, j = tid - i*20;
    float tr[NT];
    if (act){
        #pragma unroll
        for (int k=0;k<NT;++k) tr[k] = trans[i*NT+k];
        Pb[0][tid] = (i==j) ? 0.f : -1e30f;
    }
    __syncthreads();
    int cur = 0;
    for (int t=0;t<CLEN;++t){
        float m = -3.0e38f;
        if (act){
            #pragma unroll
            for (int k=0;k<NT;++k) m = fmaxf(m, tr[k] + Pb[cur][k*NT+j]);
            m += fl[t*NT+i];
            Pb[cur^1][tid] = m;
        }
        __syncthreads();
        cur ^= 1;
    }
    if (act) Pall[(size_t)c*(NT*NT) + tid] = Pb[cur][tid];
}

// ---------------------------------------------------------------------------
// V2: sequential chunk scan -> fv at chunk starts + terminal argmax/score.
// ---------------------------------------------------------------------------
__global__ __launch_bounds__(128) void vit_scan(
    const float* __restrict__ Pall, const float* __restrict__ trans,
    float* __restrict__ fvstart, float* __restrict__ dout, int* __restrict__ bestws)
{
    __shared__ float Pb[NT*NT];
    __shared__ float fv[NT];
    const int tid = threadIdx.x;
    float4 pn = {0.f,0.f,0.f,0.f};
    if (tid<100) pn = ((const float4*)Pall)[tid];
    if (tid<NT) fv[tid] = (tid==18) ? 0.f : -10000.f;
    for (int c=0;c<CHUNKS;++c){
        if (tid<100) ((float4*)Pb)[tid] = pn;
        if (tid<100 && c+1<CHUNKS) pn = ((const float4*)(Pall + (size_t)(c+1)*(NT*NT)))[tid];
        __syncthreads();
        if (tid<NT) fvstart[c*NT+tid] = fv[tid];
        float nf = -3.0e38f;
        if (tid<NT){
            #pragma unroll
            for (int j=0;j<NT;++j) nf = fmaxf(nf, Pb[tid*NT+j] + fv[j]);
        }
        __syncthreads();
        if (tid<NT) fv[tid] = nf;
    }
    __syncthreads();
    if (tid==0){
        float best = -3.0e38f; int bidx = 0;
        for (int j=0;j<NT;++j){
            float tv = fv[j] + trans[19*NT+j];
            if (tv > best){ best = tv; bidx = j; }
        }
        dout[0] = best;
        bestws[0] = bidx;
    }
}

// ---------------------------------------------------------------------------
// V3: exact per-step replay (reference argmax semantics) -> backpointers + H_c
// ---------------------------------------------------------------------------
__global__ __launch_bounds__(64) void vit_replay(
    const float* __restrict__ featsp, const float* __restrict__ btag,
    const float* __restrict__ trans, const float* __restrict__ fvstart,
    unsigned int* __restrict__ bpout, int* __restrict__ Hout)
{
    __shared__ float fl[CLEN*NT];
    __shared__ float fv[NT];
    __shared__ unsigned char bp[CLEN*NT];
    const int c = blockIdx.x, tid = threadIdx.x;
    load_fl(featsp, btag, fl, c, tid, 64);
    float tr[NT];
    if (tid<NT){
        fv[tid] = fvstart[c*NT+tid];
        #pragma unroll
        for (int k=0;k<NT;++k) tr[k] = trans[tid*NT+k];
    }
    __syncthreads();
    for (int t=0;t<CLEN;++t){
        float best = 0.f; int bj = 0;
        if (tid<NT){
            best = tr[0] + fv[0];
            #pragma unroll
            for (int j=1;j<NT;++j){
                float v = tr[j] + fv[j];
                if (v > best){ best = v; bj = j; }
            }
        }
        __syncthreads();
        if (tid<NT){
            fv[tid] = best + fl[t*NT+tid];
            bp[t*NT+tid] = (unsigned char)bj;
        }
        __syncthreads();
    }
    for (int idx=tid; idx<CLEN*NT/4; idx+=64)
        bpout[(size_t)c*(CLEN*NT/4) + idx] = ((unsigned int*)bp)[idx];
    if (tid<NT){
        int m = tid;
        for (int t=CLEN-1;t>=0;--t) m = bp[t*NT+m];
        Hout[c*NT+tid] = m;
    }
}

// ---------------------------------------------------------------------------
// V4 (fused): each block walks the composed chunk maps from bestws down to
// its own chunk, then backtracks its chunk and writes the path slice.
// ---------------------------------------------------------------------------
__global__ __launch_bounds__(64) void bt_fill(
    const unsigned int* __restrict__ bpin, const int* __restrict__ Hin,
    const int* __restrict__ bestws, float* __restrict__ dout)
{
    __shared__ int Hl[CHUNKS*NT];
    __shared__ unsigned char bp[CLEN*NT];
    __shared__ float ob[CLEN];
    const int c = blockIdx.x, tid = threadIdx.x;
    for (int idx=tid; idx<CHUNKS*NT; idx+=64) Hl[idx] = Hin[idx];
    for (int idx=tid; idx<CLEN*NT/4; idx+=64)
        ((unsigned int*)bp)[idx] = bpin[(size_t)c*(CLEN*NT/4) + idx];
    __syncthreads();
    if (tid==0){
        int e = bestws[0];
        for (int cc=CHUNKS-1; cc>c; --cc) e = Hl[cc*NT+e];
        for (int t=CLEN-1;t>=0;--t){ ob[t] = (float)e; e = bp[t*NT+e]; }
    }
    __syncthreads();
    for (int idx=tid; idx<CLEN; idx+=64)
        dout[1 + c*CLEN + idx] = ob[idx];
}

// ---------------------------------------------------------------------------
extern "C" void kernel_launch(void* const* d_in, const int* in_sizes, int n_in,
                              void* d_out, int out_size, void* d_ws, size_t ws_size,
                              hipStream_t stream)
{
    const float* x    = (const float*)d_in[0];
    const float* wf   = (const float*)d_in[1];
    const float* bihf = (const float*)d_in[3];
    const float* bhhf = (const float*)d_in[4];
    const float* wb   = (const float*)d_in[5];
    const float* bihb = (const float*)d_in[7];
    const float* bhhb = (const float*)d_in[8];
    const float* wtag = (const float*)d_in[9];
    const float* btag = (const float*)d_in[10];
    const float* trans= (const float*)d_in[11];
    float* out = (float*)d_out;

    char* w = (char*)d_ws;
    ushort_t* Bh = (ushort_t*)w;         w += 2359296;    // 1536*768*2
    ushort_t* Bl = (ushort_t*)w;         w += 2359296;
    float* featsp = (float*)w;           w += 5242880;    // 4 * 16384*20 * 4B
    float* Pall  = (float*)w;            w += 204800;     // 128*400*4
    float* fvst  = (float*)w;            w += 10240;      // 128*20*4
    int* Hmap    = (int*)w;              w += 10240;      // 128*20*4
    unsigned int* bp = (unsigned int*)w; w += 327680;     // 16384*20 bytes
    int* best    = (int*)w;

    conv_kernel<<<1152, 256, 0, stream>>>(wf, wb, Bh, Bl);
    gemm_fused<<<1024, 256, 0, stream>>>(x, Bh, Bl, bihf, bhhf, bihb, bhhb,
                                         wtag, featsp);
    vit_chunkmat<<<CHUNKS, 512, 0, stream>>>(featsp, btag, trans, Pall);
    vit_scan<<<1, 128, 0, stream>>>(Pall, trans, fvst, out, best);
    vit_replay<<<CHUNKS, 64, 0, stream>>>(featsp, btag, trans, fvst, bp, Hmap);
    bt_fill<<<CHUNKS, 64, 0, stream>>>(bp, Hmap, best, out);
}

// Round 7
// 393.854 us; speedup vs baseline: 1.1364x; 1.0983x over previous
//
#include <hip/hip_runtime.h>
#include <math.h>

#define HDIM 768
#define HIDD 512
#define NTOK 16384
#define NT 20
#define CHUNKS 128
#define CLEN 128

typedef unsigned short ushort_t;
typedef __attribute__((ext_vector_type(8))) short bf16x8;
typedef __attribute__((ext_vector_type(4))) float f32x4;

__device__ __forceinline__ float sigm(float x){ return 1.0f/(1.0f+expf(-x)); }

__device__ __forceinline__ ushort_t f2bf(float f){
    unsigned int u = __float_as_uint(f);
    unsigned int r = (u + 0x7fffu + ((u >> 16) & 1u)) >> 16;
    return (ushort_t)r;
}
__device__ __forceinline__ float bf2f(ushort_t b){
    return __uint_as_float(((unsigned int)b) << 16);
}

#define GLD16(gp, lp) __builtin_amdgcn_global_load_lds( \
    (const __attribute__((address_space(1))) void*)(gp), \
    (__attribute__((address_space(3))) void*)(lp), 16, 0, 0)

union U8 { ushort_t u[8]; uint4 v; };

// ---------------------------------------------------------------------------
// conv: pack w_ih_{f,b} gates {i,g,o} -> Bh/Bl bf16 (1536x768).
// ---------------------------------------------------------------------------
__global__ __launch_bounds__(256) void conv_kernel(
    const float* __restrict__ wf, const float* __restrict__ wb,
    ushort_t* __restrict__ Bh, ushort_t* __restrict__ Bl)
{
    int t = blockIdx.x*256 + threadIdx.x;          // 1536*192
    int n = t / 192, c4 = (t - n*192)*4;
    int dir = n / 768, nr = n - dir*768;
    int gate = nr >> 8, j = nr & 255;
    int wrow = j + ((gate==0)?0:((gate==1)?512:768));
    const float* src = dir ? wb : wf;
    const float4 v = *(const float4*)(src + (size_t)wrow*HDIM + c4);
    float f[4] = {v.x, v.y, v.z, v.w};
    ushort_t h[4], l[4];
    #pragma unroll
    for (int i=0;i<4;++i){
        h[i] = f2bf(f[i]);
        l[i] = f2bf(f[i] - bf2f(h[i]));
    }
    *(ushort4*)(Bh + (size_t)n*HDIM + c4) = make_ushort4(h[0],h[1],h[2],h[3]);
    *(ushort4*)(Bl + (size_t)n*HDIM + c4) = make_ushort4(l[0],l[1],l[2],l[3]);
}

// ---------------------------------------------------------------------------
// Fused split-bf16 MFMA GEMM, ONE K-loop for all 3 gates (i,g,o held in
// 3 acc sets), + gate activation + partial-feats epilogue.
// Block: 64 m-rows x 64 n-cols x one dir (q = dir*4 + j-quarter, 8 total).
// LDS 56 KB: A 8 KB single-buf (reg-converted fp32 x), B 2x24 KB dbuf
// (3 gates x h/l, streamed via global_load_lds). 48 barrier-pairs/block
// (was 144), 36 MFMA/wave per pair. x read once. Per-acc fp sequence
// identical to prior rounds -> bit-identical gate values.
// ---------------------------------------------------------------------------
__global__ __launch_bounds__(256, 2) void gemm_fused(
    const float* __restrict__ x,
    const ushort_t* __restrict__ Bh, const ushort_t* __restrict__ Bl,
    const float* __restrict__ bihf, const float* __restrict__ bhhf,
    const float* __restrict__ bihb, const float* __restrict__ bhhb,
    const float* __restrict__ wtag, float* __restrict__ featsp)
{
    __shared__ __align__(16) char smem[57344];
    ushort_t* As_h = (ushort_t*)smem;                    // 4 KB
    ushort_t* As_l = (ushort_t*)(smem + 4096);           // 4 KB
    // B: buf b at 8192 + b*24576; gate g at +g*8192 (h), +g*8192+4096 (l)
    float* hbuf = (float*)smem;                          // epilogue 32x65 f32
    float* wts  = (float*)(smem + 8448);                 // epilogue 20x64 f32

    const int tid = threadIdx.x;
    const int bx = blockIdx.x;
    const int xcd = bx & 7, bidx = bx >> 3;
    const int q = bidx & 7, mt = (bidx >> 3)*8 + xcd;    // 8 q-blocks share XCD
    const int dir = q >> 2, j0 = (q & 3)*64;
    const int row0 = mt*64;
    const float* __restrict__ bih = dir ? bihb : bihf;
    const float* __restrict__ bhh = dir ? bhhb : bhhf;

    const int lane = tid & 63, wv = tid >> 6;
    const int wm = wv >> 1, wn = wv & 1;
    const int lm = lane & 15, lq = lane >> 4;
    const int wbB = (tid & 192) * 16;                    // wave-uniform byte base

    // ---- staging decode: chunk C=tid -> (row, k8) under pair swizzle ------
    const int P_ = tid >> 3, s_ = tid & 7;
    const int q_ = s_ ^ (P_ & 7);
    const int mA = (P_ << 1) | (q_ >> 2);                // row 0..63
    const int k8s = q_ & 3;
    const float* aSrc = x + (size_t)(row0 + mA + 1)*HDIM + k8s*8;
    size_t bOff[3];
    #pragma unroll
    for (int g=0; g<3; ++g)
        bOff[g] = (size_t)(dir*768 + g*256 + j0 + mA)*HDIM + k8s*8;

    // ---- fragment ds_read byte offsets ------------------------------------
    int aoffB[2], boffB[2];
    #pragma unroll
    for (int f=0; f<2; ++f){
        int m = wm*32 + f*16 + lm;
        aoffB[f] = ((m>>1)*8 + ((((m&1)<<2)|lq) ^ ((m>>1)&7)))*16;
        int n = wn*32 + f*16 + lm;
        boffB[f] = ((n>>1)*8 + ((((n&1)<<2)|lq) ^ ((n>>1)&7)))*16;
    }

    int jcol[2];
    #pragma unroll
    for (int f=0; f<2; ++f) jcol[f] = j0 + wn*32 + f*16 + lm;

    f32x4 acc[3][2][2];                                  // [gate][fm][fn]
    #pragma unroll
    for (int g=0; g<3; ++g)
        #pragma unroll
        for (int fm=0; fm<2; ++fm)
            #pragma unroll
            for (int fn=0; fn<2; ++fn)
                acc[g][fm][fn] = (f32x4){0.f,0.f,0.f,0.f};

    uint4 rh, rl;

    // ---- initial prefetch (kt=0 -> buf0) ----------------------------------
    {
        char* bb = smem + 8192;
        #pragma unroll
        for (int g=0; g<3; ++g){
            GLD16(Bh + bOff[g], bb + g*8192 + wbB);
            GLD16(Bl + bOff[g], bb + g*8192 + 4096 + wbB);
        }
        float4 ra0 = *(const float4*)(aSrc);
        float4 ra1 = *(const float4*)(aSrc + 4);
        float f[8] = {ra0.x,ra0.y,ra0.z,ra0.w,ra1.x,ra1.y,ra1.z,ra1.w};
        U8 h8, l8;
        #pragma unroll
        for (int i=0;i<8;++i){
            ushort_t h = f2bf(f[i]);
            h8.u[i] = h; l8.u[i] = f2bf(f[i] - bf2f(h));
        }
        rh = h8.v; rl = l8.v;
    }

    #pragma unroll 1
    for (int kt=0; kt<24; ++kt){
        __syncthreads();               // prev readers done; B(kt) GLD16 drained
        *(uint4*)&As_h[tid*8] = rh;
        *(uint4*)&As_l[tid*8] = rl;
        __syncthreads();

        if (kt < 23){
            const int k0n = (kt+1)*32;
            char* bb = smem + 8192 + ((kt+1)&1)*24576;
            #pragma unroll
            for (int g=0; g<3; ++g){
                GLD16(Bh + bOff[g] + k0n, bb + g*8192 + wbB);
                GLD16(Bl + bOff[g] + k0n, bb + g*8192 + 4096 + wbB);
            }
            float4 ra0 = *(const float4*)(aSrc + k0n);
            float4 ra1 = *(const float4*)(aSrc + k0n + 4);
            float f[8] = {ra0.x,ra0.y,ra0.z,ra0.w,ra1.x,ra1.y,ra1.z,ra1.w};
            U8 h8, l8;
            #pragma unroll
            for (int i=0;i<8;++i){
                ushort_t h = f2bf(f[i]);
                h8.u[i] = h; l8.u[i] = f2bf(f[i] - bf2f(h));
            }
            rh = h8.v; rl = l8.v;
        }

        // compute tile kt
        const char* bb = smem + 8192 + (kt&1)*24576;
        bf16x8 afh[2], afl[2];
        #pragma unroll
        for (int f=0; f<2; ++f){
            afh[f] = *(const bf16x8*)(smem + aoffB[f]);
            afl[f] = *(const bf16x8*)(smem + 4096 + aoffB[f]);
        }
        #pragma unroll
        for (int g=0; g<3; ++g){
            const char* bg = bb + g*8192;
            #pragma unroll
            for (int fn=0; fn<2; ++fn){
                bf16x8 bh = *(const bf16x8*)(bg + boffB[fn]);
                bf16x8 bl = *(const bf16x8*)(bg + 4096 + boffB[fn]);
                #pragma unroll
                for (int fm=0; fm<2; ++fm){
                    acc[g][fm][fn] = __builtin_amdgcn_mfma_f32_16x16x32_bf16(
                        afh[fm], bh, acc[g][fm][fn], 0, 0, 0);
                    acc[g][fm][fn] = __builtin_amdgcn_mfma_f32_16x16x32_bf16(
                        afl[fm], bh, acc[g][fm][fn], 0, 0, 0);
                    acc[g][fm][fn] = __builtin_amdgcn_mfma_f32_16x16x32_bf16(
                        afh[fm], bl, acc[g][fm][fn], 0, 0, 0);
                }
            }
        }
    }

    // ---- epilogue: gates -> h -> partial feats ---------------------------
    float bi[2], bg_[2], bo[2];
    #pragma unroll
    for (int f=0; f<2; ++f){
        bi[f]  = bih[jcol[f]]       + bhh[jcol[f]];
        bg_[f] = bih[512 + jcol[f]] + bhh[512 + jcol[f]];
        bo[f]  = bih[768 + jcol[f]] + bhh[768 + jcol[f]];
    }
    float hv[2][2][4];
    #pragma unroll
    for (int fm=0; fm<2; ++fm)
        #pragma unroll
        for (int fn=0; fn<2; ++fn)
            #pragma unroll
            for (int r=0; r<4; ++r){
                float cv = sigm(acc[0][fm][fn][r] + bi[fn]) *
                           tanhf(acc[1][fm][fn][r] + bg_[fn]);
                hv[fm][fn][r] = sigm(acc[2][fm][fn][r] + bo[fn]) * tanhf(cv);
            }

    __syncthreads();   // all tile reads done before LDS reuse
    for (int i2=tid; i2<NT*64; i2+=256){
        int t = i2 >> 6, j = i2 & 63;
        wts[i2] = wtag[t*HIDD + dir*256 + j0 + j];
    }
    float* fq = featsp + (size_t)q * (NTOK*NT);
    #pragma unroll 1
    for (int ph=0; ph<2; ++ph){
        __syncthreads();
        if (wm == ph){
            #pragma unroll
            for (int fm=0; fm<2; ++fm)
                #pragma unroll
                for (int fn=0; fn<2; ++fn)
                    #pragma unroll
                    for (int r=0; r<4; ++r){
                        int mloc = fm*16 + lq*4 + r;        // 0..31
                        int jloc = wn*32 + fn*16 + lm;      // 0..63
                        hbuf[mloc*65 + jloc] = hv[fm][fn][r];
                    }
        }
        __syncthreads();
        const int mrow = tid & 31, grp = tid >> 5;          // 8 groups
        if (grp < 5){
            const int tg0 = grp*4;
            float s[4] = {0.f,0.f,0.f,0.f};
            for (int j=0;j<64;++j){
                float h = hbuf[mrow*65 + j];
                #pragma unroll
                for (int tt=0; tt<4; ++tt)
                    s[tt] = fmaf(h, wts[(tg0+tt)*64 + j], s[tt]);
            }
            const int mglob = row0 + ph*32 + mrow;
            #pragma unroll
            for (int tt=0; tt<4; ++tt)
                fq[(size_t)mglob*NT + tg0 + tt] = s[tt];
        }
    }
}

// ---------------------------------------------------------------------------
// fl loader: identical deterministic sum of the 8 partial buffers + btag.
// ---------------------------------------------------------------------------
__device__ __forceinline__ void load_fl(
    const float* __restrict__ featsp, const float* __restrict__ btg,
    float* fl, int c, int tid, int nthr)
{
    const int base = c*(CLEN*NT/4);
    for (int idx=tid; idx<CLEN*NT/4; idx+=nthr){
        float4 s[8];
        #pragma unroll
        for (int p=0; p<8; ++p)
            s[p] = ((const float4*)(featsp + (size_t)p*NTOK*NT))[base+idx];
        float4 v;
        v.x = ((s[0].x+s[1].x)+(s[2].x+s[3].x)) + ((s[4].x+s[5].x)+(s[6].x+s[7].x));
        v.y = ((s[0].y+s[1].y)+(s[2].y+s[3].y)) + ((s[4].y+s[5].y)+(s[6].y+s[7].y));
        v.z = ((s[0].z+s[1].z)+(s[2].z+s[3].z)) + ((s[4].z+s[5].z)+(s[6].z+s[7].z));
        v.w = ((s[0].w+s[1].w)+(s[2].w+s[3].w)) + ((s[4].w+s[5].w)+(s[6].w+s[7].w));
        int t0 = (idx*4) % 20;
        v.x += btg[t0]; v.y += btg[t0+1]; v.z += btg[t0+2]; v.w += btg[t0+3];
        ((float4*)fl)[idx] = v;
    }
}

// ---------------------------------------------------------------------------
// V1: per-chunk max-plus matrix product P_c (20x20). One block per chunk.
// ---------------------------------------------------------------------------
__global__ __launch_bounds__(512) void vit_chunkmat(
    const float* __restrict__ featsp, const float* __restrict__ btag,
    const float* __restrict__ trans, float* __restrict__ Pall)
{
    __shared__ float fl[CLEN*NT];
    __shared__ float Pb[2][NT*NT];
    const int c = blockIdx.x, tid = threadIdx.x;
    load_fl(featsp, btag, fl, c, tid, 512);
    const bool act = tid < NT*NT;
    const int i = tid/20, j = tid - i*20;
    float tr[NT];
    if (act){
        #pragma unroll
        for (int k=0;k<NT;++k) tr[k] = trans[i*NT+k];
        Pb[0][tid] = (i==j) ? 0.f : -1e30f;
    }
    __syncthreads();
    int cur = 0;
    for (int t=0;t<CLEN;++t){
        float m = -3.0e38f;
        if (act){
            #pragma unroll
            for (int k=0;k<NT;++k) m = fmaxf(m, tr[k] + Pb[cur][k*NT+j]);
            m += fl[t*NT+i];
            Pb[cur^1][tid] = m;
        }
        __syncthreads();
        cur ^= 1;
    }
    if (act) Pall[(size_t)c*(NT*NT) + tid] = Pb[cur][tid];
}

// ---------------------------------------------------------------------------
// V3 (+scan fold): each block recomputes the deterministic Pall-prefix scan
// to get its fvstart (bit-identical across blocks), then exact per-step
// replay (reference argmax semantics) -> backpointers + composed map H_c.
// Block CHUNKS-1 also emits terminal path_score + best state.
// ---------------------------------------------------------------------------
__global__ __launch_bounds__(128) void vit_replay(
    const float* __restrict__ featsp, const float* __restrict__ btag,
    const float* __restrict__ trans, const float* __restrict__ Pall,
    unsigned int* __restrict__ bpout, int* __restrict__ Hout,
    float* __restrict__ dout, int* __restrict__ bestws)
{
    __shared__ float fl[CLEN*NT];
    __shared__ float fv[NT];
    __shared__ float Pb[NT*NT];
    __shared__ unsigned char bp[CLEN*NT];
    const int c = blockIdx.x, tid = threadIdx.x;
    load_fl(featsp, btag, fl, c, tid, 128);
    if (tid<NT) fv[tid] = (tid==18) ? 0.f : -10000.f;   // START=18
    float4 pn = {0.f,0.f,0.f,0.f};
    if (tid<100 && c>0) pn = ((const float4*)Pall)[tid];
    __syncthreads();
    // prefix scan over chunk matrices (same op order as before -> identical)
    for (int cc=0; cc<c; ++cc){
        if (tid<100) ((float4*)Pb)[tid] = pn;
        if (tid<100 && cc+1<c) pn = ((const float4*)(Pall + (size_t)(cc+1)*(NT*NT)))[tid];
        __syncthreads();
        float nf = -3.0e38f;
        if (tid<NT){
            #pragma unroll
            for (int j=0;j<NT;++j) nf = fmaxf(nf, Pb[tid*NT+j] + fv[j]);
        }
        __syncthreads();
        if (tid<NT) fv[tid] = nf;
        __syncthreads();
    }
    float tr[NT];
    if (tid<NT){
        #pragma unroll
        for (int k=0;k<NT;++k) tr[k] = trans[tid*NT+k];
    }
    __syncthreads();
    for (int t=0;t<CLEN;++t){
        float best = 0.f; int bj = 0;
        if (tid<NT){
            best = tr[0] + fv[0];
            #pragma unroll
            for (int j=1;j<NT;++j){
                float v = tr[j] + fv[j];
                if (v > best){ best = v; bj = j; }      // strict > == first-win
            }
        }
        __syncthreads();
        if (tid<NT){
            fv[tid] = best + fl[t*NT+tid];
            bp[t*NT+tid] = (unsigned char)bj;
        }
        __syncthreads();
    }
    for (int idx=tid; idx<CLEN*NT/4; idx+=128)
        bpout[(size_t)c*(CLEN*NT/4) + idx] = ((unsigned int*)bp)[idx];
    if (tid<NT){
        int m = tid;
        for (int t=CLEN-1;t>=0;--t) m = bp[t*NT+m];
        Hout[c*NT+tid] = m;
    }
    if (c == CHUNKS-1 && tid == 0){
        float best = -3.0e38f; int bidx = 0;
        for (int j=0;j<NT;++j){
            float tv = fv[j] + trans[19*NT+j];          // STOP row = 19
            if (tv > best){ best = tv; bidx = j; }
        }
        dout[0] = best;
        bestws[0] = bidx;
    }
}

// ---------------------------------------------------------------------------
// V4: each block walks the composed chunk maps from bestws down to its own
// chunk, then backtracks its chunk and writes the path slice.
// ---------------------------------------------------------------------------
__global__ __launch_bounds__(64) void bt_fill(
    const unsigned int* __restrict__ bpin, const int* __restrict__ Hin,
    const int* __restrict__ bestws, float* __restrict__ dout)
{
    __shared__ int Hl[CHUNKS*NT];
    __shared__ unsigned char bp[CLEN*NT];
    __shared__ float ob[CLEN];
    const int c = blockIdx.x, tid = threadIdx.x;
    for (int idx=tid; idx<CHUNKS*NT; idx+=64) Hl[idx] = Hin[idx];
    for (int idx=tid; idx<CLEN*NT/4; idx+=64)
        ((unsigned int*)bp)[idx] = bpin[(size_t)c*(CLEN*NT/4) + idx];
    __syncthreads();
    if (tid==0){
        int e = bestws[0];
        for (int cc=CHUNKS-1; cc>c; --cc) e = Hl[cc*NT+e];
        for (int t=CLEN-1;t>=0;--t){ ob[t] = (float)e; e = bp[t*NT+e]; }
    }
    __syncthreads();
    for (int idx=tid; idx<CLEN; idx+=64)
        dout[1 + c*CLEN + idx] = ob[idx];
}

// ---------------------------------------------------------------------------
extern "C" void kernel_launch(void* const* d_in, const int* in_sizes, int n_in,
                              void* d_out, int out_size, void* d_ws, size_t ws_size,
                              hipStream_t stream)
{
    const float* x    = (const float*)d_in[0];
    const float* wf   = (const float*)d_in[1];
    const float* bihf = (const float*)d_in[3];
    const float* bhhf = (const float*)d_in[4];
    const float* wb   = (const float*)d_in[5];
    const float* bihb = (const float*)d_in[7];
    const float* bhhb = (const float*)d_in[8];
    const float* wtag = (const float*)d_in[9];
    const float* btag = (const float*)d_in[10];
    const float* trans= (const float*)d_in[11];
    float* out = (float*)d_out;

    char* w = (char*)d_ws;
    ushort_t* Bh = (ushort_t*)w;         w += 2359296;    // 1536*768*2
    ushort_t* Bl = (ushort_t*)w;         w += 2359296;
    float* featsp = (float*)w;           w += 10485760;   // 8 * 16384*20 * 4B
    float* Pall  = (float*)w;            w += 204800;     // 128*400*4
    int* Hmap    = (int*)w;              w += 10240;      // 128*20*4
    unsigned int* bp = (unsigned int*)w; w += 327680;     // 16384*20 bytes
    int* best    = (int*)w;

    conv_kernel<<<1152, 256, 0, stream>>>(wf, wb, Bh, Bl);
    gemm_fused<<<2048, 256, 0, stream>>>(x, Bh, Bl, bihf, bhhf, bihb, bhhb,
                                         wtag, featsp);
    vit_chunkmat<<<CHUNKS, 512, 0, stream>>>(featsp, btag, trans, Pall);
    vit_replay<<<CHUNKS, 128, 0, stream>>>(featsp, btag, trans, Pall, bp, Hmap,
                                           out, best);
    bt_fill<<<CHUNKS, 64, 0, stream>>>(bp, Hmap, best, out);
}

// Round 8
// 391.723 us; speedup vs baseline: 1.1426x; 1.0054x over previous
//
#include <hip/hip_runtime.h>
#include <math.h>

#define HDIM 768
#define HIDD 512
#define NTOK 16384
#define NT 20
#define CHUNKS 128
#define CLEN 128

typedef unsigned short ushort_t;
typedef __attribute__((ext_vector_type(8))) short bf16x8;
typedef __attribute__((ext_vector_type(4))) float f32x4;

__device__ __forceinline__ float sigm(float x){ return 1.0f/(1.0f+expf(-x)); }

__device__ __forceinline__ ushort_t f2bf(float f){
    unsigned int u = __float_as_uint(f);
    unsigned int r = (u + 0x7fffu + ((u >> 16) & 1u)) >> 16;
    return (ushort_t)r;
}
__device__ __forceinline__ float bf2f(ushort_t b){
    return __uint_as_float(((unsigned int)b) << 16);
}

#define GLD16(gp, lp) __builtin_amdgcn_global_load_lds( \
    (const __attribute__((address_space(1))) void*)(gp), \
    (__attribute__((address_space(3))) void*)(lp), 16, 0, 0)

// ---------------------------------------------------------------------------
// conv: blocks [0,1152) pack B (w_ih f/b gates i,g,o) -> Bh/Bl (1536x768);
// blocks [1152,13440) split x rows 1..16384 -> Ah/Al (16384x768).
// ---------------------------------------------------------------------------
__global__ __launch_bounds__(256) void conv_kernel(
    const float* __restrict__ x,
    const float* __restrict__ wf, const float* __restrict__ wb,
    ushort_t* __restrict__ Ah, ushort_t* __restrict__ Al,
    ushort_t* __restrict__ Bh, ushort_t* __restrict__ Bl)
{
    const int bid = blockIdx.x;
    if (bid < 1152){
        int t = bid*256 + threadIdx.x;                 // 1536*192
        int n = t / 192, c4 = (t - n*192)*4;
        int dir = n / 768, nr = n - dir*768;
        int gate = nr >> 8, j = nr & 255;
        int wrow = j + ((gate==0)?0:((gate==1)?512:768));
        const float* src = dir ? wb : wf;
        const float4 v = *(const float4*)(src + (size_t)wrow*HDIM + c4);
        float f[4] = {v.x, v.y, v.z, v.w};
        ushort_t h[4], l[4];
        #pragma unroll
        for (int i=0;i<4;++i){
            h[i] = f2bf(f[i]);
            l[i] = f2bf(f[i] - bf2f(h[i]));
        }
        *(ushort4*)(Bh + (size_t)n*HDIM + c4) = make_ushort4(h[0],h[1],h[2],h[3]);
        *(ushort4*)(Bl + (size_t)n*HDIM + c4) = make_ushort4(l[0],l[1],l[2],l[3]);
    } else {
        int t = (bid-1152)*256 + threadIdx.x;          // 16384*192
        int row = t / 192, c4 = (t - row*192)*4;
        const float4 v = *(const float4*)(x + (size_t)(row+1)*HDIM + c4);
        float f[4] = {v.x, v.y, v.z, v.w};
        ushort_t h[4], l[4];
        #pragma unroll
        for (int i=0;i<4;++i){
            h[i] = f2bf(f[i]);
            l[i] = f2bf(f[i] - bf2f(h[i]));
        }
        *(ushort4*)(Ah + (size_t)row*HDIM + c4) = make_ushort4(h[0],h[1],h[2],h[3]);
        *(ushort4*)(Al + (size_t)row*HDIM + c4) = make_ushort4(l[0],l[1],l[2],l[3]);
    }
}

// ---------------------------------------------------------------------------
// Split-bf16 MFMA GEMM, one K-loop, 3 gates, + activation + partial feats.
// Block: 64 m-rows x 64 n-cols x one dir. 64 KB LDS: A dbuf 2x8 KB +
// B dbuf 2x24 KB, both filled purely by global_load_lds (no ds_write, no
// conversion in-loop). ONE barrier per kt: it drains GLD16(kt) issued a
// full compute-phase earlier (latency hidden); GLD16(kt+1) issues right
// after the barrier into the alternate buffer (safe: all waves' reads of
// that buffer drained via the barrier's lgkmcnt(0)).
// Per-acc fp sequence identical to R7 -> bit-identical gate values.
// ---------------------------------------------------------------------------
__global__ __launch_bounds__(256, 2) void gemm_fused(
    const ushort_t* __restrict__ Ah, const ushort_t* __restrict__ Al,
    const ushort_t* __restrict__ Bh, const ushort_t* __restrict__ Bl,
    const float* __restrict__ bihf, const float* __restrict__ bhhf,
    const float* __restrict__ bihb, const float* __restrict__ bhhb,
    const float* __restrict__ wtag, float* __restrict__ featsp)
{
    __shared__ __align__(16) char smem[65536];
    // A: buf b at b*8192   (h +0, l +4096)
    // B: 16384 + b*24576 + g*8192  (h +0, l +4096)
    float* hbuf = (float*)smem;                          // epilogue 32x65 f32
    float* wts  = (float*)(smem + 8448);                 // epilogue 20x64 f32

    const int tid = threadIdx.x;
    const int bx = blockIdx.x;
    const int xcd = bx & 7, bidx = bx >> 3;
    const int q = bidx & 7, mt = (bidx >> 3)*8 + xcd;    // 8 q-blocks share XCD
    const int dir = q >> 2, j0 = (q & 3)*64;
    const int row0 = mt*64;
    const float* __restrict__ bih = dir ? bihb : bihf;
    const float* __restrict__ bhh = dir ? bhhb : bhhf;

    const int lane = tid & 63, wv = tid >> 6;
    const int wm = wv >> 1, wn = wv & 1;
    const int lm = lane & 15, lq = lane >> 4;
    const int wbB = (tid & 192) * 16;                    // wave-uniform byte base

    // ---- staging decode: chunk C=tid -> (row, k8) under pair swizzle ------
    const int P_ = tid >> 3, s_ = tid & 7;
    const int q_ = s_ ^ (P_ & 7);
    const int mA = (P_ << 1) | (q_ >> 2);                // row 0..63
    const int k8s = q_ & 3;
    const size_t aoff = (size_t)(row0 + mA)*HDIM + k8s*8;
    size_t bOff[3];
    #pragma unroll
    for (int g=0; g<3; ++g)
        bOff[g] = (size_t)(dir*768 + g*256 + j0 + mA)*HDIM + k8s*8;

    // ---- fragment ds_read byte offsets (within a 4 KB region) -------------
    int aoffB[2], boffB[2];
    #pragma unroll
    for (int f=0; f<2; ++f){
        int m = wm*32 + f*16 + lm;
        aoffB[f] = ((m>>1)*8 + ((((m&1)<<2)|lq) ^ ((m>>1)&7)))*16;
        int n = wn*32 + f*16 + lm;
        boffB[f] = ((n>>1)*8 + ((((n&1)<<2)|lq) ^ ((n>>1)&7)))*16;
    }

    int jcol[2];
    #pragma unroll
    for (int f=0; f<2; ++f) jcol[f] = j0 + wn*32 + f*16 + lm;

    f32x4 acc[3][2][2];                                  // [gate][fm][fn]
    #pragma unroll
    for (int g=0; g<3; ++g)
        #pragma unroll
        for (int fm=0; fm<2; ++fm)
            #pragma unroll
            for (int fn=0; fn<2; ++fn)
                acc[g][fm][fn] = (f32x4){0.f,0.f,0.f,0.f};

    // ---- prologue: GLD16(kt=0) -> buf0 ------------------------------------
    {
        GLD16(Ah + aoff, smem + wbB);
        GLD16(Al + aoff, smem + 4096 + wbB);
        char* bb = smem + 16384;
        #pragma unroll
        for (int g=0; g<3; ++g){
            GLD16(Bh + bOff[g], bb + g*8192 + wbB);
            GLD16(Bl + bOff[g], bb + g*8192 + 4096 + wbB);
        }
    }

    #pragma unroll 1
    for (int kt=0; kt<24; ++kt){
        __syncthreads();     // drains GLD16(kt); prev readers of alt buf done

        if (kt < 23){
            const int k0n = (kt+1)*32;
            char* ab = smem + ((kt+1)&1)*8192;
            char* bb = smem + 16384 + ((kt+1)&1)*24576;
            GLD16(Ah + aoff + k0n, ab + wbB);
            GLD16(Al + aoff + k0n, ab + 4096 + wbB);
            #pragma unroll
            for (int g=0; g<3; ++g){
                GLD16(Bh + bOff[g] + k0n, bb + g*8192 + wbB);
                GLD16(Bl + bOff[g] + k0n, bb + g*8192 + 4096 + wbB);
            }
        }

        const char* ab = smem + (kt&1)*8192;
        const char* bb = smem + 16384 + (kt&1)*24576;
        bf16x8 afh[2], afl[2];
        #pragma unroll
        for (int f=0; f<2; ++f){
            afh[f] = *(const bf16x8*)(ab + aoffB[f]);
            afl[f] = *(const bf16x8*)(ab + 4096 + aoffB[f]);
        }
        #pragma unroll
        for (int g=0; g<3; ++g){
            const char* bg = bb + g*8192;
            #pragma unroll
            for (int fn=0; fn<2; ++fn){
                bf16x8 bh = *(const bf16x8*)(bg + boffB[fn]);
                bf16x8 bl = *(const bf16x8*)(bg + 4096 + boffB[fn]);
                #pragma unroll
                for (int fm=0; fm<2; ++fm){
                    acc[g][fm][fn] = __builtin_amdgcn_mfma_f32_16x16x32_bf16(
                        afh[fm], bh, acc[g][fm][fn], 0, 0, 0);
                    acc[g][fm][fn] = __builtin_amdgcn_mfma_f32_16x16x32_bf16(
                        afl[fm], bh, acc[g][fm][fn], 0, 0, 0);
                    acc[g][fm][fn] = __builtin_amdgcn_mfma_f32_16x16x32_bf16(
                        afh[fm], bl, acc[g][fm][fn], 0, 0, 0);
                }
            }
        }
    }

    // ---- epilogue: gates -> h -> partial feats ----------------------------
    float bi[2], bg_[2], bo[2];
    #pragma unroll
    for (int f=0; f<2; ++f){
        bi[f]  = bih[jcol[f]]       + bhh[jcol[f]];
        bg_[f] = bih[512 + jcol[f]] + bhh[512 + jcol[f]];
        bo[f]  = bih[768 + jcol[f]] + bhh[768 + jcol[f]];
    }
    float hv[2][2][4];
    #pragma unroll
    for (int fm=0; fm<2; ++fm)
        #pragma unroll
        for (int fn=0; fn<2; ++fn)
            #pragma unroll
            for (int r=0; r<4; ++r){
                float cv = sigm(acc[0][fm][fn][r] + bi[fn]) *
                           tanhf(acc[1][fm][fn][r] + bg_[fn]);
                hv[fm][fn][r] = sigm(acc[2][fm][fn][r] + bo[fn]) * tanhf(cv);
            }

    __syncthreads();   // all tile reads done before LDS reuse
    for (int i2=tid; i2<NT*64; i2+=256){
        int t = i2 >> 6, j = i2 & 63;
        wts[i2] = wtag[t*HIDD + dir*256 + j0 + j];
    }
    float* fq = featsp + (size_t)q * (NTOK*NT);
    #pragma unroll 1
    for (int ph=0; ph<2; ++ph){
        __syncthreads();
        if (wm == ph){
            #pragma unroll
            for (int fm=0; fm<2; ++fm)
                #pragma unroll
                for (int fn=0; fn<2; ++fn)
                    #pragma unroll
                    for (int r=0; r<4; ++r){
                        int mloc = fm*16 + lq*4 + r;        // 0..31
                        int jloc = wn*32 + fn*16 + lm;      // 0..63
                        hbuf[mloc*65 + jloc] = hv[fm][fn][r];
                    }
        }
        __syncthreads();
        const int mrow = tid & 31, grp = tid >> 5;          // 8 groups
        if (grp < 5){
            const int tg0 = grp*4;
            float s[4] = {0.f,0.f,0.f,0.f};
            for (int j=0;j<64;++j){
                float h = hbuf[mrow*65 + j];
                #pragma unroll
                for (int tt=0; tt<4; ++tt)
                    s[tt] = fmaf(h, wts[(tg0+tt)*64 + j], s[tt]);
            }
            const int mglob = row0 + ph*32 + mrow;
            #pragma unroll
            for (int tt=0; tt<4; ++tt)
                fq[(size_t)mglob*NT + tg0 + tt] = s[tt];
        }
    }
}

// ---------------------------------------------------------------------------
// fl loader: identical deterministic sum of the 8 partial buffers + btag.
// ---------------------------------------------------------------------------
__device__ __forceinline__ void load_fl(
    const float* __restrict__ featsp, const float* __restrict__ btg,
    float* fl, int c, int tid, int nthr)
{
    const int base = c*(CLEN*NT/4);
    for (int idx=tid; idx<CLEN*NT/4; idx+=nthr){
        float4 s[8];
        #pragma unroll
        for (int p=0; p<8; ++p)
            s[p] = ((const float4*)(featsp + (size_t)p*NTOK*NT))[base+idx];
        float4 v;
        v.x = ((s[0].x+s[1].x)+(s[2].x+s[3].x)) + ((s[4].x+s[5].x)+(s[6].x+s[7].x));
        v.y = ((s[0].y+s[1].y)+(s[2].y+s[3].y)) + ((s[4].y+s[5].y)+(s[6].y+s[7].y));
        v.z = ((s[0].z+s[1].z)+(s[2].z+s[3].z)) + ((s[4].z+s[5].z)+(s[6].z+s[7].z));
        v.w = ((s[0].w+s[1].w)+(s[2].w+s[3].w)) + ((s[4].w+s[5].w)+(s[6].w+s[7].w));
        int t0 = (idx*4) % 20;
        v.x += btg[t0]; v.y += btg[t0+1]; v.z += btg[t0+2]; v.w += btg[t0+3];
        ((float4*)fl)[idx] = v;
    }
}

// ---------------------------------------------------------------------------
// V1: per-chunk max-plus matrix product P_c (20x20). One block per chunk.
// ---------------------------------------------------------------------------
__global__ __launch_bounds__(512) void vit_chunkmat(
    const float* __restrict__ featsp, const float* __restrict__ btag,
    const float* __restrict__ trans, float* __restrict__ Pall)
{
    __shared__ float fl[CLEN*NT];
    __shared__ float Pb[2][NT*NT];
    const int c = blockIdx.x, tid = threadIdx.x;
    load_fl(featsp, btag, fl, c, tid, 512);
    const bool act = tid < NT*NT;
    const int i = tid/20, j = tid - i*20;
    float tr[NT];
    if (act){
        #pragma unroll
        for (int k=0;k<NT;++k) tr[k] = trans[i*NT+k];
        Pb[0][tid] = (i==j) ? 0.f : -1e30f;
    }
    __syncthreads();
    int cur = 0;
    for (int t=0;t<CLEN;++t){
        float m = -3.0e38f;
        if (act){
            #pragma unroll
            for (int k=0;k<NT;++k) m = fmaxf(m, tr[k] + Pb[cur][k*NT+j]);
            m += fl[t*NT+i];
            Pb[cur^1][tid] = m;
        }
        __syncthreads();
        cur ^= 1;
    }
    if (act) Pall[(size_t)c*(NT*NT) + tid] = Pb[cur][tid];
}

// ---------------------------------------------------------------------------
// V3 (+scan fold): each block recomputes the deterministic Pall-prefix scan
// to get its fvstart, then exact per-step replay -> backpointers + H_c.
// Block CHUNKS-1 also emits terminal path_score + best state.
// ---------------------------------------------------------------------------
__global__ __launch_bounds__(128) void vit_replay(
    const float* __restrict__ featsp, const float* __restrict__ btag,
    const float* __restrict__ trans, const float* __restrict__ Pall,
    unsigned int* __restrict__ bpout, int* __restrict__ Hout,
    float* __restrict__ dout, int* __restrict__ bestws)
{
    __shared__ float fl[CLEN*NT];
    __shared__ float fv[NT];
    __shared__ float Pb[NT*NT];
    __shared__ unsigned char bp[CLEN*NT];
    const int c = blockIdx.x, tid = threadIdx.x;
    load_fl(featsp, btag, fl, c, tid, 128);
    if (tid<NT) fv[tid] = (tid==18) ? 0.f : -10000.f;   // START=18
    float4 pn = {0.f,0.f,0.f,0.f};
    if (tid<100 && c>0) pn = ((const float4*)Pall)[tid];
    __syncthreads();
    for (int cc=0; cc<c; ++cc){
        if (tid<100) ((float4*)Pb)[tid] = pn;
        if (tid<100 && cc+1<c) pn = ((const float4*)(Pall + (size_t)(cc+1)*(NT*NT)))[tid];
        __syncthreads();
        float nf = -3.0e38f;
        if (tid<NT){
            #pragma unroll
            for (int j=0;j<NT;++j) nf = fmaxf(nf, Pb[tid*NT+j] + fv[j]);
        }
        __syncthreads();
        if (tid<NT) fv[tid] = nf;
        __syncthreads();
    }
    float tr[NT];
    if (tid<NT){
        #pragma unroll
        for (int k=0;k<NT;++k) tr[k] = trans[tid*NT+k];
    }
    __syncthreads();
    for (int t=0;t<CLEN;++t){
        float best = 0.f; int bj = 0;
        if (tid<NT){
            best = tr[0] + fv[0];
            #pragma unroll
            for (int j=1;j<NT;++j){
                float v = tr[j] + fv[j];
                if (v > best){ best = v; bj = j; }      // strict > == first-win
            }
        }
        __syncthreads();
        if (tid<NT){
            fv[tid] = best + fl[t*NT+tid];
            bp[t*NT+tid] = (unsigned char)bj;
        }
        __syncthreads();
    }
    for (int idx=tid; idx<CLEN*NT/4; idx+=128)
        bpout[(size_t)c*(CLEN*NT/4) + idx] = ((unsigned int*)bp)[idx];
    if (tid<NT){
        int m = tid;
        for (int t=CLEN-1;t>=0;--t) m = bp[t*NT+m];
        Hout[c*NT+tid] = m;
    }
    if (c == CHUNKS-1 && tid == 0){
        float best = -3.0e38f; int bidx = 0;
        for (int j=0;j<NT;++j){
            float tv = fv[j] + trans[19*NT+j];          // STOP row = 19
            if (tv > best){ best = tv; bidx = j; }
        }
        dout[0] = best;
        bestws[0] = bidx;
    }
}

// ---------------------------------------------------------------------------
// V4: each block walks the composed chunk maps from bestws down to its own
// chunk, then backtracks its chunk and writes the path slice.
// ---------------------------------------------------------------------------
__global__ __launch_bounds__(64) void bt_fill(
    const unsigned int* __restrict__ bpin, const int* __restrict__ Hin,
    const int* __restrict__ bestws, float* __restrict__ dout)
{
    __shared__ int Hl[CHUNKS*NT];
    __shared__ unsigned char bp[CLEN*NT];
    __shared__ float ob[CLEN];
    const int c = blockIdx.x, tid = threadIdx.x;
    for (int idx=tid; idx<CHUNKS*NT; idx+=64) Hl[idx] = Hin[idx];
    for (int idx=tid; idx<CLEN*NT/4; idx+=64)
        ((unsigned int*)bp)[idx] = bpin[(size_t)c*(CLEN*NT/4) + idx];
    __syncthreads();
    if (tid==0){
        int e = bestws[0];
        for (int cc=CHUNKS-1; cc>c; --cc) e = Hl[cc*NT+e];
        for (int t=CLEN-1;t>=0;--t){ ob[t] = (float)e; e = bp[t*NT+e]; }
    }
    __syncthreads();
    for (int idx=tid; idx<CLEN; idx+=64)
        dout[1 + c*CLEN + idx] = ob[idx];
}

// ---------------------------------------------------------------------------
extern "C" void kernel_launch(void* const* d_in, const int* in_sizes, int n_in,
                              void* d_out, int out_size, void* d_ws, size_t ws_size,
                              hipStream_t stream)
{
    const float* x    = (const float*)d_in[0];
    const float* wf   = (const float*)d_in[1];
    const float* bihf = (const float*)d_in[3];
    const float* bhhf = (const float*)d_in[4];
    const float* wb   = (const float*)d_in[5];
    const float* bihb = (const float*)d_in[7];
    const float* bhhb = (const float*)d_in[8];
    const float* wtag = (const float*)d_in[9];
    const float* btag = (const float*)d_in[10];
    const float* trans= (const float*)d_in[11];
    float* out = (float*)d_out;

    char* w = (char*)d_ws;
    ushort_t* Ah = (ushort_t*)w;         w += 25165824;   // 16384*768*2
    ushort_t* Al = (ushort_t*)w;         w += 25165824;
    ushort_t* Bh = (ushort_t*)w;         w += 2359296;    // 1536*768*2
    ushort_t* Bl = (ushort_t*)w;         w += 2359296;
    float* featsp = (float*)w;           w += 10485760;   // 8 * 16384*20 * 4B
    float* Pall  = (float*)w;            w += 204800;     // 128*400*4
    int* Hmap    = (int*)w;              w += 10240;      // 128*20*4
    unsigned int* bp = (unsigned int*)w; w += 327680;     // 16384*20 bytes
    int* best    = (int*)w;

    conv_kernel<<<13440, 256, 0, stream>>>(x, wf, wb, Ah, Al, Bh, Bl);
    gemm_fused<<<2048, 256, 0, stream>>>(Ah, Al, Bh, Bl, bihf, bhhf, bihb, bhhb,
                                         wtag, featsp);
    vit_chunkmat<<<CHUNKS, 512, 0, stream>>>(featsp, btag, trans, Pall);
    vit_replay<<<CHUNKS, 128, 0, stream>>>(featsp, btag, trans, Pall, bp, Hmap,
                                           out, best);
    bt_fill<<<CHUNKS, 64, 0, stream>>>(bp, Hmap, best, out);
}

// Round 9
// 368.948 us; speedup vs baseline: 1.2131x; 1.0617x over previous
//
#include <hip/hip_runtime.h>
#include <math.h>

#define HDIM 768
#define HIDD 512
#define NTOK 16384
#define NT 20
#define CHUNKS 128
#define CLEN 128

typedef unsigned short ushort_t;
typedef __attribute__((ext_vector_type(8))) short bf16x8;
typedef __attribute__((ext_vector_type(4))) float f32x4;

__device__ __forceinline__ float sigm(float x){ return 1.0f/(1.0f+expf(-x)); }

__device__ __forceinline__ ushort_t f2bf(float f){
    unsigned int u = __float_as_uint(f);
    unsigned int r = (u + 0x7fffu + ((u >> 16) & 1u)) >> 16;
    return (ushort_t)r;
}
__device__ __forceinline__ float bf2f(ushort_t b){
    return __uint_as_float(((unsigned int)b) << 16);
}

#define GLD16(gp, lp) __builtin_amdgcn_global_load_lds( \
    (const __attribute__((address_space(1))) void*)(gp), \
    (__attribute__((address_space(3))) void*)(lp), 16, 0, 0)

// ---------------------------------------------------------------------------
// conv: blocks [0,1152) pack B (w_ih f/b gates i,g,o) -> Bh/Bl (1536x768);
// blocks [1152,13440) split x rows 1..16384 -> Ah/Al (16384x768).
// ---------------------------------------------------------------------------
__global__ __launch_bounds__(256) void conv_kernel(
    const float* __restrict__ x,
    const float* __restrict__ wf, const float* __restrict__ wb,
    ushort_t* __restrict__ Ah, ushort_t* __restrict__ Al,
    ushort_t* __restrict__ Bh, ushort_t* __restrict__ Bl)
{
    const int bid = blockIdx.x;
    if (bid < 1152){
        int t = bid*256 + threadIdx.x;                 // 1536*192
        int n = t / 192, c4 = (t - n*192)*4;
        int dir = n / 768, nr = n - dir*768;
        int gate = nr >> 8, j = nr & 255;
        int wrow = j + ((gate==0)?0:((gate==1)?512:768));
        const float* src = dir ? wb : wf;
        const float4 v = *(const float4*)(src + (size_t)wrow*HDIM + c4);
        float f[4] = {v.x, v.y, v.z, v.w};
        ushort_t h[4], l[4];
        #pragma unroll
        for (int i=0;i<4;++i){
            h[i] = f2bf(f[i]);
            l[i] = f2bf(f[i] - bf2f(h[i]));
        }
        *(ushort4*)(Bh + (size_t)n*HDIM + c4) = make_ushort4(h[0],h[1],h[2],h[3]);
        *(ushort4*)(Bl + (size_t)n*HDIM + c4) = make_ushort4(l[0],l[1],l[2],l[3]);
    } else {
        int t = (bid-1152)*256 + threadIdx.x;          // 16384*192
        int row = t / 192, c4 = (t - row*192)*4;
        const float4 v = *(const float4*)(x + (size_t)(row+1)*HDIM + c4);
        float f[4] = {v.x, v.y, v.z, v.w};
        ushort_t h[4], l[4];
        #pragma unroll
        for (int i=0;i<4;++i){
            h[i] = f2bf(f[i]);
            l[i] = f2bf(f[i] - bf2f(h[i]));
        }
        *(ushort4*)(Ah + (size_t)row*HDIM + c4) = make_ushort4(h[0],h[1],h[2],h[3]);
        *(ushort4*)(Al + (size_t)row*HDIM + c4) = make_ushort4(l[0],l[1],l[2],l[3]);
    }
}

// ---------------------------------------------------------------------------
// Split-bf16 MFMA GEMM, one K-loop, 3 gates, + activation + partial feats.
// Block: 128 m-rows x 64 n-cols x one dir. 4 waves of 64m x 32n x 3 gates
// (acc 24 f32x4) -> wave-level LDS reads drop from 64 B/KFLOP to 40:
// the binding pipe (R8 analysis: LDS read BW, 4x wave re-read of tiles).
// 80 KB LDS: A dbuf 2x16 KB + B dbuf 2x24 KB, all via global_load_lds;
// one barrier per kt. Per-acc fp sequence identical -> bit-identical gates.
// ---------------------------------------------------------------------------
__global__ __launch_bounds__(256, 2) void gemm_fused(
    const ushort_t* __restrict__ Ah, const ushort_t* __restrict__ Al,
    const ushort_t* __restrict__ Bh, const ushort_t* __restrict__ Bl,
    const float* __restrict__ bihf, const float* __restrict__ bhhf,
    const float* __restrict__ bihb, const float* __restrict__ bhhb,
    const float* __restrict__ wtag, float* __restrict__ featsp)
{
    __shared__ __align__(16) char smem[81920];
    // A: buf b at b*16384: Ah rows0-63 @0, rows64-127 @4096, Al @8192/@12288
    // B: 32768 + b*24576 + g*8192 (h @0, l @4096)
    float* hbuf = (float*)smem;                          // epilogue 64x65 f32
    float* wts  = (float*)(smem + 16640);                // epilogue 20x64 f32

    const int tid = threadIdx.x;
    const int bx = blockIdx.x;
    const int xcd = bx & 7, g3 = bx >> 3;
    const int q = g3 & 7, mt = (g3 >> 3)*8 + xcd;        // 8 q-blocks share XCD
    const int dir = q >> 2, j0 = (q & 3)*64;
    const int row0 = mt*128;
    const float* __restrict__ bih = dir ? bihb : bihf;
    const float* __restrict__ bhh = dir ? bhhb : bhhf;

    const int lane = tid & 63, wv = tid >> 6;
    const int wm = wv >> 1, wn = wv & 1;
    const int lm = lane & 15, lq = lane >> 4;
    const int wbB = (tid & 192) * 16;                    // wave-uniform byte base

    // ---- staging decode: chunk C=tid -> (row, k8) under pair swizzle ------
    const int P_ = tid >> 3, s_ = tid & 7;
    const int q_ = s_ ^ (P_ & 7);
    const int mA = (P_ << 1) | (q_ >> 2);                // row 0..63 in group
    const int k8s = q_ & 3;
    const size_t aoff0 = (size_t)(row0 + mA)*HDIM + k8s*8;        // rows 0-63
    const size_t aoff1 = (size_t)(row0 + 64 + mA)*HDIM + k8s*8;   // rows 64-127
    size_t bOff[3];
    #pragma unroll
    for (int g=0; g<3; ++g)
        bOff[g] = (size_t)(dir*768 + g*256 + j0 + mA)*HDIM + k8s*8;

    // ---- fragment ds_read byte offsets ------------------------------------
    int aoffB[4], boffB[2];
    #pragma unroll
    for (int f=0; f<4; ++f){
        int m = wm*64 + f*16 + lm;                       // 0..127
        int rg = m >> 6, r = m & 63;
        aoffB[f] = rg*4096 + ((r>>1)*8 + ((((r&1)<<2)|lq) ^ ((r>>1)&7)))*16;
    }
    #pragma unroll
    for (int f=0; f<2; ++f){
        int n = wn*32 + f*16 + lm;                       // 0..63
        boffB[f] = ((n>>1)*8 + ((((n&1)<<2)|lq) ^ ((n>>1)&7)))*16;
    }

    int jcol[2];
    #pragma unroll
    for (int f=0; f<2; ++f) jcol[f] = j0 + wn*32 + f*16 + lm;

    f32x4 acc[3][4][2];                                  // [gate][fm][fn]
    #pragma unroll
    for (int g=0; g<3; ++g)
        #pragma unroll
        for (int fm=0; fm<4; ++fm)
            #pragma unroll
            for (int fn=0; fn<2; ++fn)
                acc[g][fm][fn] = (f32x4){0.f,0.f,0.f,0.f};

    // ---- prologue: GLD16(kt=0) -> buf0 ------------------------------------
    {
        GLD16(Ah + aoff0, smem + wbB);
        GLD16(Ah + aoff1, smem + 4096 + wbB);
        GLD16(Al + aoff0, smem + 8192 + wbB);
        GLD16(Al + aoff1, smem + 12288 + wbB);
        char* bb = smem + 32768;
        #pragma unroll
        for (int g=0; g<3; ++g){
            GLD16(Bh + bOff[g], bb + g*8192 + wbB);
            GLD16(Bl + bOff[g], bb + g*8192 + 4096 + wbB);
        }
    }

    #pragma unroll 1
    for (int kt=0; kt<24; ++kt){
        __syncthreads();     // drains GLD16(kt); prev readers of alt buf done

        if (kt < 23){
            const int k0n = (kt+1)*32;
            char* ab = smem + ((kt+1)&1)*16384;
            char* bb = smem + 32768 + ((kt+1)&1)*24576;
            GLD16(Ah + aoff0 + k0n, ab + wbB);
            GLD16(Ah + aoff1 + k0n, ab + 4096 + wbB);
            GLD16(Al + aoff0 + k0n, ab + 8192 + wbB);
            GLD16(Al + aoff1 + k0n, ab + 12288 + wbB);
            #pragma unroll
            for (int g=0; g<3; ++g){
                GLD16(Bh + bOff[g] + k0n, bb + g*8192 + wbB);
                GLD16(Bl + bOff[g] + k0n, bb + g*8192 + 4096 + wbB);
            }
        }

        const char* ab = smem + (kt&1)*16384;
        const char* bb = smem + 32768 + (kt&1)*24576;
        bf16x8 afh[4], afl[4];
        #pragma unroll
        for (int f=0; f<4; ++f){
            afh[f] = *(const bf16x8*)(ab + aoffB[f]);
            afl[f] = *(const bf16x8*)(ab + 8192 + aoffB[f]);
        }
        #pragma unroll
        for (int g=0; g<3; ++g){
            const char* bg = bb + g*8192;
            #pragma unroll
            for (int fn=0; fn<2; ++fn){
                bf16x8 bh = *(const bf16x8*)(bg + boffB[fn]);
                bf16x8 bl = *(const bf16x8*)(bg + 4096 + boffB[fn]);
                #pragma unroll
                for (int fm=0; fm<4; ++fm){
                    acc[g][fm][fn] = __builtin_amdgcn_mfma_f32_16x16x32_bf16(
                        afh[fm], bh, acc[g][fm][fn], 0, 0, 0);
                    acc[g][fm][fn] = __builtin_amdgcn_mfma_f32_16x16x32_bf16(
                        afl[fm], bh, acc[g][fm][fn], 0, 0, 0);
                    acc[g][fm][fn] = __builtin_amdgcn_mfma_f32_16x16x32_bf16(
                        afh[fm], bl, acc[g][fm][fn], 0, 0, 0);
                }
            }
        }
    }

    // ---- epilogue: gates -> h -> partial feats ----------------------------
    float bi[2], bg_[2], bo[2];
    #pragma unroll
    for (int f=0; f<2; ++f){
        bi[f]  = bih[jcol[f]]       + bhh[jcol[f]];
        bg_[f] = bih[512 + jcol[f]] + bhh[512 + jcol[f]];
        bo[f]  = bih[768 + jcol[f]] + bhh[768 + jcol[f]];
    }
    float hv[4][2][4];
    #pragma unroll
    for (int fm=0; fm<4; ++fm)
        #pragma unroll
        for (int fn=0; fn<2; ++fn)
            #pragma unroll
            for (int r=0; r<4; ++r){
                float cv = sigm(acc[0][fm][fn][r] + bi[fn]) *
                           tanhf(acc[1][fm][fn][r] + bg_[fn]);
                hv[fm][fn][r] = sigm(acc[2][fm][fn][r] + bo[fn]) * tanhf(cv);
            }

    __syncthreads();   // all tile reads done before LDS reuse
    for (int i2=tid; i2<NT*64; i2+=256){
        int t = i2 >> 6, j = i2 & 63;
        wts[i2] = wtag[t*HIDD + dir*256 + j0 + j];
    }
    float* fq = featsp + (size_t)q * (NTOK*NT);
    #pragma unroll 1
    for (int ph=0; ph<2; ++ph){
        __syncthreads();
        if (wm == ph){
            #pragma unroll
            for (int fm=0; fm<4; ++fm)
                #pragma unroll
                for (int fn=0; fn<2; ++fn)
                    #pragma unroll
                    for (int r=0; r<4; ++r){
                        int mloc = fm*16 + lq*4 + r;        // 0..63
                        int jloc = wn*32 + fn*16 + lm;      // 0..63
                        hbuf[mloc*65 + jloc] = hv[fm][fn][r];
                    }
        }
        __syncthreads();
        const int mrow = tid & 63, grp = tid >> 6;          // 4 groups x 5 tags
        const int tg0 = grp*5;
        float s[5] = {0.f,0.f,0.f,0.f,0.f};
        for (int j=0;j<64;++j){
            float h = hbuf[mrow*65 + j];
            #pragma unroll
            for (int tt=0; tt<5; ++tt)
                s[tt] = fmaf(h, wts[(tg0+tt)*64 + j], s[tt]);
        }
        const int mglob = row0 + ph*64 + mrow;
        #pragma unroll
        for (int tt=0; tt<5; ++tt)
            fq[(size_t)mglob*NT + tg0 + tt] = s[tt];
    }
}

// ---------------------------------------------------------------------------
// fl loader: identical deterministic sum of the 8 partial buffers + btag.
// ---------------------------------------------------------------------------
__device__ __forceinline__ void load_fl(
    const float* __restrict__ featsp, const float* __restrict__ btg,
    float* fl, int c, int tid, int nthr)
{
    const int base = c*(CLEN*NT/4);
    for (int idx=tid; idx<CLEN*NT/4; idx+=nthr){
        float4 s[8];
        #pragma unroll
        for (int p=0; p<8; ++p)
            s[p] = ((const float4*)(featsp + (size_t)p*NTOK*NT))[base+idx];
        float4 v;
        v.x = ((s[0].x+s[1].x)+(s[2].x+s[3].x)) + ((s[4].x+s[5].x)+(s[6].x+s[7].x));
        v.y = ((s[0].y+s[1].y)+(s[2].y+s[3].y)) + ((s[4].y+s[5].y)+(s[6].y+s[7].y));
        v.z = ((s[0].z+s[1].z)+(s[2].z+s[3].z)) + ((s[4].z+s[5].z)+(s[6].z+s[7].z));
        v.w = ((s[0].w+s[1].w)+(s[2].w+s[3].w)) + ((s[4].w+s[5].w)+(s[6].w+s[7].w));
        int t0 = (idx*4) % 20;
        v.x += btg[t0]; v.y += btg[t0+1]; v.z += btg[t0+2]; v.w += btg[t0+3];
        ((float4*)fl)[idx] = v;
    }
}

// ---------------------------------------------------------------------------
// V1: per-chunk max-plus matrix product P_c (20x20). One block per chunk.
// ---------------------------------------------------------------------------
__global__ __launch_bounds__(512) void vit_chunkmat(
    const float* __restrict__ featsp, const float* __restrict__ btag,
    const float* __restrict__ trans, float* __restrict__ Pall)
{
    __shared__ float fl[CLEN*NT];
    __shared__ float Pb[2][NT*NT];
    const int c = blockIdx.x, tid = threadIdx.x;
    load_fl(featsp, btag, fl, c, tid, 512);
    const bool act = tid < NT*NT;
    const int i = tid/20, j = tid - i*20;
    float tr[NT];
    if (act){
        #pragma unroll
        for (int k=0;k<NT;++k) tr[k] = trans[i*NT+k];
        Pb[0][tid] = (i==j) ? 0.f : -1e30f;
    }
    __syncthreads();
    int cur = 0;
    for (int t=0;t<CLEN;++t){
        float m = -3.0e38f;
        if (act){
            #pragma unroll
            for (int k=0;k<NT;++k) m = fmaxf(m, tr[k] + Pb[cur][k*NT+j]);
            m += fl[t*NT+i];
            Pb[cur^1][tid] = m;
        }
        __syncthreads();
        cur ^= 1;
    }
    if (act) Pall[(size_t)c*(NT*NT) + tid] = Pb[cur][tid];
}

// ---------------------------------------------------------------------------
// V2: sequential chunk scan -> fv at chunk starts + terminal argmax/score.
// ---------------------------------------------------------------------------
__global__ __launch_bounds__(128) void vit_scan(
    const float* __restrict__ Pall, const float* __restrict__ trans,
    float* __restrict__ fvstart, float* __restrict__ dout, int* __restrict__ bestws)
{
    __shared__ float Pb[NT*NT];
    __shared__ float fv[NT];
    const int tid = threadIdx.x;
    float4 pn = {0.f,0.f,0.f,0.f};
    if (tid<100) pn = ((const float4*)Pall)[tid];
    if (tid<NT) fv[tid] = (tid==18) ? 0.f : -10000.f;   // START=18
    for (int c=0;c<CHUNKS;++c){
        if (tid<100) ((float4*)Pb)[tid] = pn;
        if (tid<100 && c+1<CHUNKS) pn = ((const float4*)(Pall + (size_t)(c+1)*(NT*NT)))[tid];
        __syncthreads();
        if (tid<NT) fvstart[c*NT+tid] = fv[tid];
        float nf = -3.0e38f;
        if (tid<NT){
            #pragma unroll
            for (int j=0;j<NT;++j) nf = fmaxf(nf, Pb[tid*NT+j] + fv[j]);
        }
        __syncthreads();
        if (tid<NT) fv[tid] = nf;
    }
    __syncthreads();
    if (tid==0){
        float best = -3.0e38f; int bidx = 0;
        for (int j=0;j<NT;++j){
            float tv = fv[j] + trans[19*NT+j];          // STOP row = 19
            if (tv > best){ best = tv; bidx = j; }
        }
        dout[0] = best;
        bestws[0] = bidx;
    }
}

// ---------------------------------------------------------------------------
// V3: exact per-step replay (reference argmax semantics) -> backpointers + H_c
// ---------------------------------------------------------------------------
__global__ __launch_bounds__(128) void vit_replay(
    const float* __restrict__ featsp, const float* __restrict__ btag,
    const float* __restrict__ trans, const float* __restrict__ fvstart,
    unsigned int* __restrict__ bpout, int* __restrict__ Hout)
{
    __shared__ float fl[CLEN*NT];
    __shared__ float fv[NT];
    __shared__ unsigned char bp[CLEN*NT];
    const int c = blockIdx.x, tid = threadIdx.x;
    load_fl(featsp, btag, fl, c, tid, 128);
    float tr[NT];
    if (tid<NT){
        fv[tid] = fvstart[c*NT+tid];
        #pragma unroll
        for (int k=0;k<NT;++k) tr[k] = trans[tid*NT+k];
    }
    __syncthreads();
    for (int t=0;t<CLEN;++t){
        float best = 0.f; int bj = 0;
        if (tid<NT){
            best = tr[0] + fv[0];
            #pragma unroll
            for (int j=1;j<NT;++j){
                float v = tr[j] + fv[j];
                if (v > best){ best = v; bj = j; }      // strict > == first-win
            }
        }
        __syncthreads();
        if (tid<NT){
            fv[tid] = best + fl[t*NT+tid];
            bp[t*NT+tid] = (unsigned char)bj;
        }
        __syncthreads();
    }
    for (int idx=tid; idx<CLEN*NT/4; idx+=128)
        bpout[(size_t)c*(CLEN*NT/4) + idx] = ((unsigned int*)bp)[idx];
    if (tid<NT){
        int m = tid;
        for (int t=CLEN-1;t>=0;--t) m = bp[t*NT+m];
        Hout[c*NT+tid] = m;
    }
}

// ---------------------------------------------------------------------------
// V4: each block walks the composed chunk maps from bestws down to its own
// chunk, then backtracks its chunk and writes the path slice.
// ---------------------------------------------------------------------------
__global__ __launch_bounds__(64) void bt_fill(
    const unsigned int* __restrict__ bpin, const int* __restrict__ Hin,
    const int* __restrict__ bestws, float* __restrict__ dout)
{
    __shared__ int Hl[CHUNKS*NT];
    __shared__ unsigned char bp[CLEN*NT];
    __shared__ float ob[CLEN];
    const int c = blockIdx.x, tid = threadIdx.x;
    for (int idx=tid; idx<CHUNKS*NT; idx+=64) Hl[idx] = Hin[idx];
    for (int idx=tid; idx<CLEN*NT/4; idx+=64)
        ((unsigned int*)bp)[idx] = bpin[(size_t)c*(CLEN*NT/4) + idx];
    __syncthreads();
    if (tid==0){
        int e = bestws[0];
        for (int cc=CHUNKS-1; cc>c; --cc) e = Hl[cc*NT+e];
        for (int t=CLEN-1;t>=0;--t){ ob[t] = (float)e; e = bp[t*NT+e]; }
    }
    __syncthreads();
    for (int idx=tid; idx<CLEN; idx+=64)
        dout[1 + c*CLEN + idx] = ob[idx];
}

// ---------------------------------------------------------------------------
extern "C" void kernel_launch(void* const* d_in, const int* in_sizes, int n_in,
                              void* d_out, int out_size, void* d_ws, size_t ws_size,
                              hipStream_t stream)
{
    const float* x    = (const float*)d_in[0];
    const float* wf   = (const float*)d_in[1];
    const float* bihf = (const float*)d_in[3];
    const float* bhhf = (const float*)d_in[4];
    const float* wb   = (const float*)d_in[5];
    const float* bihb = (const float*)d_in[7];
    const float* bhhb = (const float*)d_in[8];
    const float* wtag = (const float*)d_in[9];
    const float* btag = (const float*)d_in[10];
    const float* trans= (const float*)d_in[11];
    float* out = (float*)d_out;

    char* w = (char*)d_ws;
    ushort_t* Ah = (ushort_t*)w;         w += 25165824;   // 16384*768*2
    ushort_t* Al = (ushort_t*)w;         w += 25165824;
    ushort_t* Bh = (ushort_t*)w;         w += 2359296;    // 1536*768*2
    ushort_t* Bl = (ushort_t*)w;         w += 2359296;
    float* featsp = (float*)w;           w += 10485760;   // 8 * 16384*20 * 4B
    float* Pall  = (float*)w;            w += 204800;     // 128*400*4
    float* fvst  = (float*)w;            w += 10240;      // 128*20*4
    int* Hmap    = (int*)w;              w += 10240;      // 128*20*4
    unsigned int* bp = (unsigned int*)w; w += 327680;     // 16384*20 bytes
    int* best    = (int*)w;

    conv_kernel<<<13440, 256, 0, stream>>>(x, wf, wb, Ah, Al, Bh, Bl);
    gemm_fused<<<1024, 256, 0, stream>>>(Ah, Al, Bh, Bl, bihf, bhhf, bihb, bhhb,
                                         wtag, featsp);
    vit_chunkmat<<<CHUNKS, 512, 0, stream>>>(featsp, btag, trans, Pall);
    vit_scan<<<1, 128, 0, stream>>>(Pall, trans, fvst, out, best);
    vit_replay<<<CHUNKS, 128, 0, stream>>>(featsp, btag, trans, fvst, bp, Hmap);
    bt_fill<<<CHUNKS, 64, 0, stream>>>(bp, Hmap, best, out);
}